// Round 8
// baseline (428.072 us; speedup 1.0000x reference)
//
#include <hip/hip_runtime.h>
#include <cstddef>
#include <cstdint>

// Problem constants (reference: B=2, T=2048, D=1024, H=16, DH=64, NU=1024)
namespace {
constexpr int B_ = 2, T_ = 2048, D_ = 1024, H_ = 16, DH_ = 64, NU_ = 1024;
constexpr float SCALE = 0.03125f;           // NU^-0.5 = 1/32
constexpr size_t OUT_ELEMS = (size_t)B_ * T_ * NU_;   // 4,194,304
}

using f4  = __attribute__((ext_vector_type(4))) float;
using s8v = __attribute__((ext_vector_type(8))) short;   // 8 bf16 (4 VGPRs)
using s4v = __attribute__((ext_vector_type(4))) short;

#define MFMA16(a, b, c) __builtin_amdgcn_mfma_f32_16x16x32_bf16((a), (b), (c), 0, 0, 0)

// 16x16x16 bf16 MFMA (K=16): A/B = 4 bf16/lane (row=lane&15, k=(lane>>4)*4+e)
#if __has_builtin(__builtin_amdgcn_mfma_f32_16x16x16bf16_1k)
__device__ __forceinline__ f4 mfma_k16(s4v a, s4v b, f4 c) {
    return __builtin_amdgcn_mfma_f32_16x16x16bf16_1k(a, b, c, 0, 0, 0);
}
#else
__device__ __forceinline__ f4 mfma_k16(s4v a, s4v b, f4 c) {
    f4 d;
    asm volatile("v_mfma_f32_16x16x16_bf16 %0, %1, %2, %3\n\t"
                 "s_nop 7\n\ts_nop 7\n\ts_nop 2"
                 : "=v"(d) : "v"(a), "v"(b), "v"(c));
    return d;
}
#endif

__device__ __forceinline__ float4 ld4(const float* p) { return *reinterpret_cast<const float4*>(p); }
__device__ __forceinline__ void st4(float* p, const float4 v) { *reinterpret_cast<float4*>(p) = v; }
__device__ __forceinline__ short f2bf(float f) {      // fp32 -> bf16 RNE
    union { float f; uint32_t u; } v{f};
    uint32_t r = (v.u + 0x7fffu + ((v.u >> 16) & 1u)) >> 16;
    return (short)r;
}

#if __has_builtin(__builtin_amdgcn_global_load_lds)
#define HAVE_GLOAD_LDS 1
__device__ __forceinline__ void load_lds16(const void* g, void* l) {
    __builtin_amdgcn_global_load_lds(
        (const __attribute__((address_space(1))) void*)g,
        (__attribute__((address_space(3))) void*)l, 16, 0, 0);
}
#else
#define HAVE_GLOAD_LDS 0
#endif

// ---------------------------------------------------------------------------
// Convert queries/keys fp32 -> bf16 row-major. grid (N/2048, 2).
// ---------------------------------------------------------------------------
__global__ __launch_bounds__(256) void cvt_x_kernel(
    const float* __restrict__ q, const float* __restrict__ k,
    short* __restrict__ qx, short* __restrict__ kx)
{
    const float* src = blockIdx.y ? k : q;
    short* dst       = blockIdx.y ? kx : qx;
    size_t i = ((size_t)blockIdx.x * 256 + threadIdx.x) * 8;
    float4 a = ld4(src + i), b = ld4(src + i + 4);
    s8v o = { f2bf(a.x), f2bf(a.y), f2bf(a.z), f2bf(a.w),
              f2bf(b.x), f2bf(b.y), f2bf(b.z), f2bf(b.w) };
    *reinterpret_cast<s8v*>(dst + i) = o;
}

// ---------------------------------------------------------------------------
// Convert + transpose W fp32 [K][N] -> bf16 Wt [N][K]. grid (16,16,3).
// ---------------------------------------------------------------------------
__global__ __launch_bounds__(256) void cvt_w_kernel(
    const float* __restrict__ Wq, const float* __restrict__ Wk,
    const float* __restrict__ Wv, short* __restrict__ wt3)
{
    const int z = blockIdx.z;
    const float* W = (z == 0) ? Wq : (z == 1) ? Wk : Wv;
    short* dst = wt3 + (size_t)z * D_ * NU_;
    const int n0 = blockIdx.x * 64, k0 = blockIdx.y * 64;
    __shared__ float tl[64][68];
    const int rr = threadIdx.x >> 2, cc = (threadIdx.x & 3) * 16;
    const float* s = W + (size_t)(k0 + rr) * NU_ + n0 + cc;
    st4(&tl[rr][cc + 0],  ld4(s + 0));
    st4(&tl[rr][cc + 4],  ld4(s + 4));
    st4(&tl[rr][cc + 8],  ld4(s + 8));
    st4(&tl[rr][cc + 12], ld4(s + 12));
    __syncthreads();
    short* d = dst + (size_t)(n0 + rr) * D_ + k0 + cc;
#pragma unroll
    for (int c = 0; c < 4; ++c) {
        s4v o = { f2bf(tl[cc + c * 4 + 0][rr]), f2bf(tl[cc + c * 4 + 1][rr]),
                  f2bf(tl[cc + c * 4 + 2][rr]), f2bf(tl[cc + c * 4 + 3][rr]) };
        *reinterpret_cast<s4v*>(d + c * 4) = o;
    }
}

// ---------------------------------------------------------------------------
// QKV projection, bf16 MFMA: 128x128 tile, BK=64, 4 waves, global_load_lds
// width-16 into linear [128][64] LDS. XCD-chunked remap (768 = 8 x 96).
// z=0->qb, z=1->kb, z=2->vt ([bh][d][t] transposed). grid(8,32,3), 256 thr.
// ---------------------------------------------------------------------------
__global__ __launch_bounds__(256) void proj_mfma(
    const short* __restrict__ qx, const short* __restrict__ kx,
    const short* __restrict__ wt3,
    const float* __restrict__ bq, const float* __restrict__ bk,
    const float* __restrict__ bv,
    short* __restrict__ qb, short* __restrict__ kb, short* __restrict__ vt)
{
    const int lin = blockIdx.z * 256 + blockIdx.y * 8 + blockIdx.x;
    const int virt = (lin & 7) * 96 + (lin >> 3);
    const int z = virt >> 8, rem = virt & 255;
    const int m0 = (rem >> 3) * 128, n0 = (rem & 7) * 128;

    const short* __restrict__ X  = (z == 0) ? qx : kx;
    const short* __restrict__ Wt = wt3 + (size_t)z * D_ * NU_;
    const float* __restrict__ bias = (z == 0) ? bq : (z == 1) ? bk : bv;

    const int t = threadIdx.x, w = t >> 6, l = t & 63;
    const int lr = l & 15, lg = l >> 4;
    const int wr = w >> 1, wc = w & 1;

    __shared__ short Asl[128 * 64];   // [row][k] linear, 16KB
    __shared__ short Bsl[128 * 64];   // [n][k] linear, 16KB

    f4 acc[4][4];
#pragma unroll
    for (int m = 0; m < 4; ++m)
#pragma unroll
        for (int n = 0; n < 4; ++n) acc[m][n] = (f4){0.f, 0.f, 0.f, 0.f};

    for (int k0 = 0; k0 < D_; k0 += 64) {
#if HAVE_GLOAD_LDS
#pragma unroll
        for (int j = 0; j < 4; ++j) {
            const int c0 = (w * 4 + j) * 64;
            const int c  = c0 + l;
            const int row = c >> 3, qo = (c & 7) * 8;
            load_lds16(X  + (size_t)(m0 + row) * D_ + k0 + qo, (char*)Asl + (size_t)c0 * 16);
            load_lds16(Wt + (size_t)(n0 + row) * D_ + k0 + qo, (char*)Bsl + (size_t)c0 * 16);
        }
        __syncthreads();
#else
        {
            const int sr = t >> 1, sc = (t & 1) * 32;
            s8v a0 = *reinterpret_cast<const s8v*>(X  + (size_t)(m0 + sr) * D_ + k0 + sc);
            s8v a1 = *reinterpret_cast<const s8v*>(X  + (size_t)(m0 + sr) * D_ + k0 + sc + 8);
            s8v a2 = *reinterpret_cast<const s8v*>(X  + (size_t)(m0 + sr) * D_ + k0 + sc + 16);
            s8v a3 = *reinterpret_cast<const s8v*>(X  + (size_t)(m0 + sr) * D_ + k0 + sc + 24);
            s8v b0 = *reinterpret_cast<const s8v*>(Wt + (size_t)(n0 + sr) * D_ + k0 + sc);
            s8v b1 = *reinterpret_cast<const s8v*>(Wt + (size_t)(n0 + sr) * D_ + k0 + sc + 8);
            s8v b2 = *reinterpret_cast<const s8v*>(Wt + (size_t)(n0 + sr) * D_ + k0 + sc + 16);
            s8v b3 = *reinterpret_cast<const s8v*>(Wt + (size_t)(n0 + sr) * D_ + k0 + sc + 24);
            __syncthreads();
            *reinterpret_cast<s8v*>(&Asl[sr * 64 + sc])      = a0;
            *reinterpret_cast<s8v*>(&Asl[sr * 64 + sc + 8])  = a1;
            *reinterpret_cast<s8v*>(&Asl[sr * 64 + sc + 16]) = a2;
            *reinterpret_cast<s8v*>(&Asl[sr * 64 + sc + 24]) = a3;
            *reinterpret_cast<s8v*>(&Bsl[sr * 64 + sc])      = b0;
            *reinterpret_cast<s8v*>(&Bsl[sr * 64 + sc + 8])  = b1;
            *reinterpret_cast<s8v*>(&Bsl[sr * 64 + sc + 16]) = b2;
            *reinterpret_cast<s8v*>(&Bsl[sr * 64 + sc + 24]) = b3;
            __syncthreads();
        }
#endif

#pragma unroll
        for (int kk = 0; kk < 2; ++kk) {
            s8v af[4], bf[4];
#pragma unroll
            for (int m = 0; m < 4; ++m)
                af[m] = *reinterpret_cast<const s8v*>(
                    &Asl[(wr * 64 + m * 16 + lr) * 64 + kk * 32 + lg * 8]);
#pragma unroll
            for (int n = 0; n < 4; ++n)
                bf[n] = *reinterpret_cast<const s8v*>(
                    &Bsl[(wc * 64 + n * 16 + lr) * 64 + kk * 32 + lg * 8]);
#pragma unroll
            for (int m = 0; m < 4; ++m)
#pragma unroll
                for (int n = 0; n < 4; ++n)
                    acc[m][n] = MFMA16(af[m], bf[n], acc[m][n]);
        }
        __syncthreads();
    }

    if (z < 2) {
        short* __restrict__ Y = (z == 0) ? qb : kb;
#pragma unroll
        for (int n = 0; n < 4; ++n) {
            const int col = n0 + wc * 64 + n * 16 + lr;
            const float bval = bias[col];
#pragma unroll
            for (int m = 0; m < 4; ++m) {
                const int row0 = m0 + wr * 64 + m * 16 + lg * 4;
#pragma unroll
                for (int r = 0; r < 4; ++r)
                    Y[(size_t)(row0 + r) * NU_ + col] = f2bf(acc[m][n][r] + bval);
            }
        }
    } else {
#pragma unroll
        for (int n = 0; n < 4; ++n) {
            const int col = n0 + wc * 64 + n * 16 + lr;   // 0..1023
            const float bval = bias[col];
            const int hh = col >> 6, dd = col & 63;
#pragma unroll
            for (int m = 0; m < 4; ++m) {
                const int Mi = m0 + wr * 64 + m * 16 + lg * 4;
                const int bb = Mi >> 11, t0 = Mi & 2047;
                s4v o = { f2bf(acc[m][n][0] + bval), f2bf(acc[m][n][1] + bval),
                          f2bf(acc[m][n][2] + bval), f2bf(acc[m][n][3] + bval) };
                *reinterpret_cast<s4v*>(vt + ((size_t)(bb * 16 + hh) * 64 + dd) * T_ + t0) = o;
            }
        }
    }
}

// ---------------------------------------------------------------------------
// Attention pass A (PV + rowsums + out), j-split form: block = 16 q-rows;
// the 4 waves split each chunk's 64 j into 16-j slices (wave w owns
// [ch*64+w*16, +16)). Swapped QK^T's C/D output S[j=lg*4+r][q=lr] IS the
// A-fragment of mfma_16x16x16 for PV (row=lane&15=q, k=(lane>>4)*4+e=j):
// P never leaves registers (4x f2bf, zero LDS, zero shuffles). Per chunk
// per wave: 2 s8v K-loads + 4 s4v V-loads + 2 MFMA(K=32) + 4 exp +
// 4 MFMA(K=16). ~60 VGPR -> 8 waves/SIMD; no barriers in the loop.
// grid 4096, 256 threads. XCD-chunked; heavy bands first.
// ---------------------------------------------------------------------------
__global__ __launch_bounds__(256) void attn_pv_mfma(
    const short* __restrict__ qb, const short* __restrict__ kb,
    const short* __restrict__ vt, float* __restrict__ rsws,
    float* __restrict__ out)
{
    const int lin = blockIdx.x;
    const int xcd = lin & 7, v = lin >> 3;
    const int bh  = xcd * 4 + (v >> 7);
    const int g16 = 127 - (v & 127);           // heavy bands dispatch first
    const int b = bh >> 4, h = bh & 15;
    const int t = threadIdx.x, w = t >> 6, l = t & 63;
    const int lr = l & 15, lg = l >> 4;
    const int tile16 = g16 >> 2;               // last (diagonal) chunk index
    const int rloc   = (g16 & 3) * 16 + lr;    // this lane's q pos in diag chunk

    __shared__ __align__(16) float OA[4 * 64 * 16];   // 16 KB partial-O
    __shared__ float rsbuf[64];                       // 4x16 partial rowsums

    // Q fragments (B-operand of QK^T: col=lane&15=q-row, k=(lane>>4)*8+e=d)
    const short* qrow = qb + (size_t)(b * T_ + g16 * 16 + lr) * NU_ + h * DH_ + lg * 8;
    const s8v qf0 = *reinterpret_cast<const s8v*>(qrow);
    const s8v qf1 = *reinterpret_cast<const s8v*>(qrow + 32);

    f4 accO[4];
#pragma unroll
    for (int nt = 0; nt < 4; ++nt) accO[nt] = (f4){0.f, 0.f, 0.f, 0.f};
    float rsum = 0.f;
    const f4 zf = (f4){0.f, 0.f, 0.f, 0.f};

    // K A-frag row = lane&15 -> j = ch*64 + w*16 + lr, d = lg*8 (+32)
    const short* kptr = kb + (size_t)(b * T_ + w * 16 + lr) * NU_ + h * DH_ + lg * 8;
    // V B-frag: col=lane&15 -> d = nt*16 + lr, k -> j = ch*64 + w*16 + lg*4 + e
    const short* vptr = vt + (size_t)(bh * 64 + lr) * T_ + w * 16 + lg * 4;
    const int jl0 = w * 16 + lg * 4;           // lane's j offset within chunk

    for (int ch = 0; ch <= tile16; ++ch) {
        const short* kr = kptr + (size_t)(ch * 64) * NU_;
        s8v kf0 = *reinterpret_cast<const s8v*>(kr);
        s8v kf1 = *reinterpret_cast<const s8v*>(kr + 32);
        const short* vr = vptr + ch * 64;      // V loads issue early
        s4v vb0 = *reinterpret_cast<const s4v*>(vr);
        s4v vb1 = *reinterpret_cast<const s4v*>(vr + (size_t)16 * T_);
        s4v vb2 = *reinterpret_cast<const s4v*>(vr + (size_t)32 * T_);
        s4v vb3 = *reinterpret_cast<const s4v*>(vr + (size_t)48 * T_);

        // swapped QK^T: S[j = jl0 + r][q = lr]
        f4 a = MFMA16(kf0, qf0, zf);
        f4 s = MFMA16(kf1, qf1, a);

        float e[4];
#pragma unroll
        for (int r = 0; r < 4; ++r) {
            float vv = __expf(s[r] * SCALE);
            if (ch == tile16 && (jl0 + r > rloc)) vv = 0.f;
            e[r] = vv;
        }
        rsum += (e[0] + e[1]) + (e[2] + e[3]);
        s4v pa = { f2bf(e[0]), f2bf(e[1]), f2bf(e[2]), f2bf(e[3]) };

        accO[0] = mfma_k16(pa, vb0, accO[0]);
        accO[1] = mfma_k16(pa, vb1, accO[1]);
        accO[2] = mfma_k16(pa, vb2, accO[2]);
        accO[3] = mfma_k16(pa, vb3, accO[3]);
    }

    // rowsum: lanes (lg, lr) hold disjoint j-partials for q=lr -> sum over lg
    rsum += __shfl_xor(rsum, 16);
    rsum += __shfl_xor(rsum, 32);              // full wave-partial for row lr

    if (lg == 0) rsbuf[w * 16 + lr] = rsum;
#pragma unroll
    for (int nt = 0; nt < 4; ++nt)
        st4(&OA[(size_t)(w * 64 + l) * 16 + nt * 4], *(const float4*)&accO[nt]);
    __syncthreads();

    // cross-wave reduce: wave w produces out cols [w*16, w*16+16)
    float osum[4];
#pragma unroll
    for (int r = 0; r < 4; ++r) osum[r] = 0.f;
#pragma unroll
    for (int wv = 0; wv < 4; ++wv) {
        float4 p = *(const float4*)&OA[(size_t)(wv * 64 + l) * 16 + w * 4];
#pragma unroll
        for (int r = 0; r < 4; ++r) osum[r] += (&p.x)[r];
    }
#pragma unroll
    for (int r = 0; r < 4; ++r) {
        const int ro = lg * 4 + r;             // local row 0..15
        const float rt = rsbuf[ro] + rsbuf[16 + ro] + rsbuf[32 + ro] + rsbuf[48 + ro];
        out[(size_t)(b * T_ + g16 * 16 + ro) * NU_ + h * DH_ + w * 16 + lr] =
            osum[r] / rt;
    }
    if (w == 0 && t < 16)
        rsws[(size_t)bh * T_ + g16 * 16 + t] =
            rsbuf[t] + rsbuf[16 + t] + rsbuf[32 + t] + rsbuf[48 + t];
}

// ---------------------------------------------------------------------------
// Attention pass B (weights): block = 64 q-rows x 256 j-cols (4 chunks).
// Reads rsws; recomputes swapped QK^T; CACHED fp32 weight stores (st4 — L2
// merges the per-row 64B segments into full lines; nontemporal stores caused
// 1.66x write amplification in round 6). grid 8192, 256 threads.
// ---------------------------------------------------------------------------
__global__ __launch_bounds__(256) void attn_wts_mfma(
    const short* __restrict__ qb, const short* __restrict__ kb,
    const float* __restrict__ rsws, float* __restrict__ wts)
{
    const int lin = blockIdx.x;
    const int xcd = lin & 7, v = lin >> 3;
    const int bh  = xcd * 4 + (v >> 8);
    const int qt  = 31 - ((v >> 3) & 31);      // heavy q-tiles first
    const int jb  = v & 7;
    const int b = bh >> 4, h = bh & 15;
    const int r0 = qt * 64;
    const int t = threadIdx.x, w = t >> 6, l = t & 63;
    const int lr = l & 15, lg = l >> 4;

    const short* qrow = qb + (size_t)(b * T_ + r0 + w * 16 + lr) * NU_ + h * DH_ + lg * 8;
    const s8v qf0 = *reinterpret_cast<const s8v*>(qrow);
    const s8v qf1 = *reinterpret_cast<const s8v*>(qrow + 32);
    const f4 zf = (f4){0.f, 0.f, 0.f, 0.f};

    const int iRow = r0 + w * 16 + lr;          // this lane's q-row
    const float inv = 1.f / rsws[(size_t)bh * T_ + iRow];
    float* const wrow = &wts[((size_t)bh * T_ + iRow) * T_];
    const short* kbase0 = kb + (size_t)(b * T_) * NU_ + h * DH_ + lg * 8;

#pragma unroll
    for (int cx = 0; cx < 4; ++cx) {
        const int ch = jb * 4 + cx;
        const int jc = ch * 64;
        if (ch <= qt) {
            const bool diag = (ch == qt);
            f4 s[4];
            const short* kbase = kbase0 + (size_t)jc * NU_;
#pragma unroll
            for (int nt = 0; nt < 4; ++nt) {
                const short* kr = kbase + (size_t)(nt * 16 + lr) * NU_;
                s8v kf0 = *reinterpret_cast<const s8v*>(kr);
                s8v kf1 = *reinterpret_cast<const s8v*>(kr + 32);
                f4 a = MFMA16(kf0, qf0, zf);
                s[nt] = MFMA16(kf1, qf1, a);
            }
#pragma unroll
            for (int nt = 0; nt < 4; ++nt) {
                float4 o;
                float* e = &o.x;
#pragma unroll
                for (int r = 0; r < 4; ++r) {
                    float vv = __expf(s[nt][r] * SCALE) * inv;
                    if (diag && (nt * 16 + lg * 4 + r > w * 16 + lr)) vv = 0.f;
                    e[r] = vv;
                }
                st4(wrow + jc + nt * 16 + lg * 4, o);
            }
        } else {
            // fully above the diagonal: block covers 64 rows x 64 cols
            float* dst = &wts[((size_t)bh * T_ + r0 + (t >> 2)) * T_ + jc + (t & 3) * 16];
            const float4 z4 = make_float4(0.f, 0.f, 0.f, 0.f);
            st4(dst + 0, z4); st4(dst + 4, z4); st4(dst + 8, z4); st4(dst + 12, z4);
        }
    }
}

// ---------------------------------------------------------------------------
extern "C" void kernel_launch(void* const* d_in, const int* in_sizes, int n_in,
                              void* d_out, int out_size, void* d_ws, size_t ws_size,
                              hipStream_t stream)
{
    const float* queries = (const float*)d_in[0];
    const float* keys    = (const float*)d_in[1];
    const float* Wq = (const float*)d_in[2];
    const float* bq = (const float*)d_in[3];
    const float* Wk = (const float*)d_in[4];
    const float* bk = (const float*)d_in[5];
    const float* Wv = (const float*)d_in[6];
    const float* bv = (const float*)d_in[7];

    float* out = (float*)d_out;                 // [B,T,NU]
    float* wts = out + OUT_ELEMS;               // [B,H,T,T]

    // workspace (bf16 shorts unless noted), total ~44.3 MB:
    short* qx = (short*)d_ws;                               // queries bf16 [4096][1024]
    short* kx = qx + (size_t)B_ * T_ * D_;                  // keys bf16
    short* wt = kx + (size_t)B_ * T_ * D_;                  // Wt bf16 [3][N][K]
    short* qb = wt + (size_t)3 * D_ * NU_;                  // q proj bf16 [4096][1024]
    short* kb = qb + (size_t)B_ * T_ * NU_;                 // k proj bf16
    short* vt = kb + (size_t)B_ * T_ * NU_;                 // v proj bf16, [bh][d][t]
    float* rsws = (float*)(vt + (size_t)B_ * T_ * NU_);     // rowsums [bh][t]

    cvt_x_kernel<<<dim3((B_ * T_ * D_) / 2048, 2), 256, 0, stream>>>(queries, keys, qx, kx);
    cvt_w_kernel<<<dim3(16, 16, 3), 256, 0, stream>>>(Wq, Wk, Wv, wt);
    proj_mfma<<<dim3(8, 32, 3), 256, 0, stream>>>(
        qx, kx, wt, bq, bk, bv, qb, kb, vt);
    attn_pv_mfma<<<dim3(4096), 256, 0, stream>>>(qb, kb, vt, rsws, out);
    attn_wts_mfma<<<dim3(8192), 256, 0, stream>>>(qb, kb, rsws, wts);
}

// Round 9
// 368.184 us; speedup vs baseline: 1.1627x; 1.1627x over previous
//
#include <hip/hip_runtime.h>
#include <cstddef>
#include <cstdint>

// Problem constants (reference: B=2, T=2048, D=1024, H=16, DH=64, NU=1024)
namespace {
constexpr int B_ = 2, T_ = 2048, D_ = 1024, H_ = 16, DH_ = 64, NU_ = 1024;
constexpr float SCALE = 0.03125f;           // NU^-0.5 = 1/32
constexpr size_t OUT_ELEMS = (size_t)B_ * T_ * NU_;   // 4,194,304
}

using f4  = __attribute__((ext_vector_type(4))) float;
using s8v = __attribute__((ext_vector_type(8))) short;   // 8 bf16 (4 VGPRs)
using s4v = __attribute__((ext_vector_type(4))) short;

#define MFMA16(a, b, c) __builtin_amdgcn_mfma_f32_16x16x32_bf16((a), (b), (c), 0, 0, 0)

__device__ __forceinline__ float4 ld4(const float* p) { return *reinterpret_cast<const float4*>(p); }
__device__ __forceinline__ void st4(float* p, const float4 v) { *reinterpret_cast<float4*>(p) = v; }
__device__ __forceinline__ short f2bf(float f) {      // fp32 -> bf16 RNE
    union { float f; uint32_t u; } v{f};
    uint32_t r = (v.u + 0x7fffu + ((v.u >> 16) & 1u)) >> 16;
    return (short)r;
}

#if __has_builtin(__builtin_amdgcn_global_load_lds)
#define HAVE_GLOAD_LDS 1
__device__ __forceinline__ void load_lds16(const void* g, void* l) {
    __builtin_amdgcn_global_load_lds(
        (const __attribute__((address_space(1))) void*)g,
        (__attribute__((address_space(3))) void*)l, 16, 0, 0);
}
#else
#define HAVE_GLOAD_LDS 0
#endif

// ---------------------------------------------------------------------------
// Convert queries/keys fp32 -> bf16 row-major. grid (N/2048, 2).
// ---------------------------------------------------------------------------
__global__ __launch_bounds__(256) void cvt_x_kernel(
    const float* __restrict__ q, const float* __restrict__ k,
    short* __restrict__ qx, short* __restrict__ kx)
{
    const float* src = blockIdx.y ? k : q;
    short* dst       = blockIdx.y ? kx : qx;
    size_t i = ((size_t)blockIdx.x * 256 + threadIdx.x) * 8;
    float4 a = ld4(src + i), b = ld4(src + i + 4);
    s8v o = { f2bf(a.x), f2bf(a.y), f2bf(a.z), f2bf(a.w),
              f2bf(b.x), f2bf(b.y), f2bf(b.z), f2bf(b.w) };
    *reinterpret_cast<s8v*>(dst + i) = o;
}

// ---------------------------------------------------------------------------
// Convert + transpose W fp32 [K][N] -> bf16 Wt [N][K]. grid (16,16,3).
// ---------------------------------------------------------------------------
__global__ __launch_bounds__(256) void cvt_w_kernel(
    const float* __restrict__ Wq, const float* __restrict__ Wk,
    const float* __restrict__ Wv, short* __restrict__ wt3)
{
    const int z = blockIdx.z;
    const float* W = (z == 0) ? Wq : (z == 1) ? Wk : Wv;
    short* dst = wt3 + (size_t)z * D_ * NU_;
    const int n0 = blockIdx.x * 64, k0 = blockIdx.y * 64;
    __shared__ float tl[64][68];
    const int rr = threadIdx.x >> 2, cc = (threadIdx.x & 3) * 16;
    const float* s = W + (size_t)(k0 + rr) * NU_ + n0 + cc;
    st4(&tl[rr][cc + 0],  ld4(s + 0));
    st4(&tl[rr][cc + 4],  ld4(s + 4));
    st4(&tl[rr][cc + 8],  ld4(s + 8));
    st4(&tl[rr][cc + 12], ld4(s + 12));
    __syncthreads();
    short* d = dst + (size_t)(n0 + rr) * D_ + k0 + cc;
#pragma unroll
    for (int c = 0; c < 4; ++c) {
        s4v o = { f2bf(tl[cc + c * 4 + 0][rr]), f2bf(tl[cc + c * 4 + 1][rr]),
                  f2bf(tl[cc + c * 4 + 2][rr]), f2bf(tl[cc + c * 4 + 3][rr]) };
        *reinterpret_cast<s4v*>(d + c * 4) = o;
    }
}

// ---------------------------------------------------------------------------
// Weights zero-fill: fully-above-diagonal (qt, jb) blocks only (jb*4 > qt).
// Per-instruction 1KB-contiguous stores: each st4 covers one full row segment
// with 64 lanes x 16B. Launched early (no dependencies) to stream at fill
// rate. grid 8192 (same mapping as score kernel; early-exit others), 256 thr.
// ---------------------------------------------------------------------------
__global__ __launch_bounds__(256) void attn_wts_fill(float* __restrict__ wts)
{
    const int lin = blockIdx.x;
    const int xcd = lin & 7, v = lin >> 3;
    const int bh  = xcd * 4 + (v >> 8);
    const int qt  = 31 - ((v >> 3) & 31);
    const int jb  = v & 7;
    if (jb * 4 <= qt) return;                  // has score work -> not ours

    const int t = threadIdx.x, w = t >> 6, l = t & 63;
    float* base = &wts[((size_t)bh * T_ + qt * 64 + w * 16) * T_ + jb * 256 + l * 4];
    const float4 z4 = make_float4(0.f, 0.f, 0.f, 0.f);
#pragma unroll
    for (int r = 0; r < 16; ++r)
        st4(base + (size_t)r * T_, z4);
}

// ---------------------------------------------------------------------------
// QKV projection, bf16 MFMA: 128x128 tile, BK=64, 4 waves, global_load_lds
// width-16 into linear [128][64] LDS. XCD-chunked remap (768 = 8 x 96).
// z=0->qb, z=1->kb, z=2->vt ([bh][d][t] transposed). grid(8,32,3), 256 thr.
// ---------------------------------------------------------------------------
__global__ __launch_bounds__(256) void proj_mfma(
    const short* __restrict__ qx, const short* __restrict__ kx,
    const short* __restrict__ wt3,
    const float* __restrict__ bq, const float* __restrict__ bk,
    const float* __restrict__ bv,
    short* __restrict__ qb, short* __restrict__ kb, short* __restrict__ vt)
{
    const int lin = blockIdx.z * 256 + blockIdx.y * 8 + blockIdx.x;
    const int virt = (lin & 7) * 96 + (lin >> 3);
    const int z = virt >> 8, rem = virt & 255;
    const int m0 = (rem >> 3) * 128, n0 = (rem & 7) * 128;

    const short* __restrict__ X  = (z == 0) ? qx : kx;
    const short* __restrict__ Wt = wt3 + (size_t)z * D_ * NU_;
    const float* __restrict__ bias = (z == 0) ? bq : (z == 1) ? bk : bv;

    const int t = threadIdx.x, w = t >> 6, l = t & 63;
    const int lr = l & 15, lg = l >> 4;
    const int wr = w >> 1, wc = w & 1;

    __shared__ short Asl[128 * 64];   // [row][k] linear, 16KB
    __shared__ short Bsl[128 * 64];   // [n][k] linear, 16KB

    f4 acc[4][4];
#pragma unroll
    for (int m = 0; m < 4; ++m)
#pragma unroll
        for (int n = 0; n < 4; ++n) acc[m][n] = (f4){0.f, 0.f, 0.f, 0.f};

    for (int k0 = 0; k0 < D_; k0 += 64) {
#if HAVE_GLOAD_LDS
#pragma unroll
        for (int j = 0; j < 4; ++j) {
            const int c0 = (w * 4 + j) * 64;
            const int c  = c0 + l;
            const int row = c >> 3, qo = (c & 7) * 8;
            load_lds16(X  + (size_t)(m0 + row) * D_ + k0 + qo, (char*)Asl + (size_t)c0 * 16);
            load_lds16(Wt + (size_t)(n0 + row) * D_ + k0 + qo, (char*)Bsl + (size_t)c0 * 16);
        }
        __syncthreads();
#else
        {
            const int sr = t >> 1, sc = (t & 1) * 32;
            s8v a0 = *reinterpret_cast<const s8v*>(X  + (size_t)(m0 + sr) * D_ + k0 + sc);
            s8v a1 = *reinterpret_cast<const s8v*>(X  + (size_t)(m0 + sr) * D_ + k0 + sc + 8);
            s8v a2 = *reinterpret_cast<const s8v*>(X  + (size_t)(m0 + sr) * D_ + k0 + sc + 16);
            s8v a3 = *reinterpret_cast<const s8v*>(X  + (size_t)(m0 + sr) * D_ + k0 + sc + 24);
            s8v b0 = *reinterpret_cast<const s8v*>(Wt + (size_t)(n0 + sr) * D_ + k0 + sc);
            s8v b1 = *reinterpret_cast<const s8v*>(Wt + (size_t)(n0 + sr) * D_ + k0 + sc + 8);
            s8v b2 = *reinterpret_cast<const s8v*>(Wt + (size_t)(n0 + sr) * D_ + k0 + sc + 16);
            s8v b3 = *reinterpret_cast<const s8v*>(Wt + (size_t)(n0 + sr) * D_ + k0 + sc + 24);
            __syncthreads();
            *reinterpret_cast<s8v*>(&Asl[sr * 64 + sc])      = a0;
            *reinterpret_cast<s8v*>(&Asl[sr * 64 + sc + 8])  = a1;
            *reinterpret_cast<s8v*>(&Asl[sr * 64 + sc + 16]) = a2;
            *reinterpret_cast<s8v*>(&Asl[sr * 64 + sc + 24]) = a3;
            *reinterpret_cast<s8v*>(&Bsl[sr * 64 + sc])      = b0;
            *reinterpret_cast<s8v*>(&Bsl[sr * 64 + sc + 8])  = b1;
            *reinterpret_cast<s8v*>(&Bsl[sr * 64 + sc + 16]) = b2;
            *reinterpret_cast<s8v*>(&Bsl[sr * 64 + sc + 24]) = b3;
            __syncthreads();
        }
#endif

#pragma unroll
        for (int kk = 0; kk < 2; ++kk) {
            s8v af[4], bf[4];
#pragma unroll
            for (int m = 0; m < 4; ++m)
                af[m] = *reinterpret_cast<const s8v*>(
                    &Asl[(wr * 64 + m * 16 + lr) * 64 + kk * 32 + lg * 8]);
#pragma unroll
            for (int n = 0; n < 4; ++n)
                bf[n] = *reinterpret_cast<const s8v*>(
                    &Bsl[(wc * 64 + n * 16 + lr) * 64 + kk * 32 + lg * 8]);
#pragma unroll
            for (int m = 0; m < 4; ++m)
#pragma unroll
                for (int n = 0; n < 4; ++n)
                    acc[m][n] = MFMA16(af[m], bf[n], acc[m][n]);
        }
        __syncthreads();
    }

    if (z < 2) {
        short* __restrict__ Y = (z == 0) ? qb : kb;
#pragma unroll
        for (int n = 0; n < 4; ++n) {
            const int col = n0 + wc * 64 + n * 16 + lr;
            const float bval = bias[col];
#pragma unroll
            for (int m = 0; m < 4; ++m) {
                const int row0 = m0 + wr * 64 + m * 16 + lg * 4;
#pragma unroll
                for (int r = 0; r < 4; ++r)
                    Y[(size_t)(row0 + r) * NU_ + col] = f2bf(acc[m][n][r] + bval);
            }
        }
    } else {
#pragma unroll
        for (int n = 0; n < 4; ++n) {
            const int col = n0 + wc * 64 + n * 16 + lr;   // 0..1023
            const float bval = bias[col];
            const int hh = col >> 6, dd = col & 63;
#pragma unroll
            for (int m = 0; m < 4; ++m) {
                const int Mi = m0 + wr * 64 + m * 16 + lg * 4;
                const int bb = Mi >> 11, t0 = Mi & 2047;
                s4v o = { f2bf(acc[m][n][0] + bval), f2bf(acc[m][n][1] + bval),
                          f2bf(acc[m][n][2] + bval), f2bf(acc[m][n][3] + bval) };
                *reinterpret_cast<s4v*>(vt + ((size_t)(bb * 16 + hh) * 64 + dd) * T_ + t0) = o;
            }
        }
    }
}

// ---------------------------------------------------------------------------
// Attention pass A (PV + rowsums + out): block = 16 q-rows (g16 band), the
// block's 4 waves SPLIT the causal chunk range (wave w takes chunks w, w+4,
// ...), each accumulating partial rsum/accO. Two-barrier LDS reduction (OA
// aliases the dead P buffer) combines partials; stores out + rsws.
// grid 4096, 256 threads. XCD-chunked; heavy bands first. (R5 structure —
// ping-pong K (R7) was neutral, j-split (R8) regressed; keep this form.)
// ---------------------------------------------------------------------------
__global__ __launch_bounds__(256) void attn_pv_mfma(
    const short* __restrict__ qb, const short* __restrict__ kb,
    const short* __restrict__ vt, float* __restrict__ rsws,
    float* __restrict__ out)
{
    const int lin = blockIdx.x;
    const int xcd = lin & 7, v = lin >> 3;
    const int bh  = xcd * 4 + (v >> 7);
    const int g16 = 127 - (v & 127);           // heavy bands dispatch first
    const int b = bh >> 4, h = bh & 15;
    const int t = threadIdx.x, w = t >> 6, l = t & 63;
    const int lr = l & 15, lg = l >> 4;
    const int tile16 = g16 >> 2;               // last (diagonal) chunk index
    const int rloc   = (g16 & 3) * 16 + lr;    // q-row pos within diag chunk

    __shared__ __align__(16) char smem[16 * 1024 + 256];
    short* Pl    = (short*)smem;               // per-wave 16x64 bf16 (loop)
    float* OA    = (float*)smem;               // 4x64x16 f32 (after barrier)
    float* rsbuf = (float*)(smem + 16 * 1024); // 4x16 partial rowsums

    // Q fragments: all 4 waves share the same 16 rows (B-operand: col=lr)
    const short* qrow = qb + (size_t)(b * T_ + g16 * 16 + lr) * NU_ + h * DH_ + lg * 8;
    const s8v qf0 = *reinterpret_cast<const s8v*>(qrow);
    const s8v qf1 = *reinterpret_cast<const s8v*>(qrow + 32);

    f4 accO[4];
#pragma unroll
    for (int nt = 0; nt < 4; ++nt) accO[nt] = (f4){0.f, 0.f, 0.f, 0.f};
    float rsum = 0.f;
    const f4 zf = (f4){0.f, 0.f, 0.f, 0.f};
    const int sw = (lr & 7) << 3;              // P swizzle keyed on q-row
    const short* kbase0 = kb + (size_t)(b * T_) * NU_ + h * DH_ + lg * 8;

    for (int ch = w; ch <= tile16; ch += 4) {
        const int jc = ch * 64;
        const bool diag = (ch == tile16);

        // swapped QK^T: s[nt][r] = S[q=lr][j = nt*16 + lg*4 + r]
        f4 s[4];
        const short* kbase = kbase0 + (size_t)jc * NU_;
#pragma unroll
        for (int nt = 0; nt < 4; ++nt) {
            const short* kr = kbase + (size_t)(nt * 16 + lr) * NU_;
            s8v kf0 = *reinterpret_cast<const s8v*>(kr);
            s8v kf1 = *reinterpret_cast<const s8v*>(kr + 32);
            f4 a = MFMA16(kf0, qf0, zf);
            s[nt] = MFMA16(kf1, qf1, a);
        }

        // exp + mask; in-lane rowsum; pack 4 bf16 -> one b64 store per nt
#pragma unroll
        for (int nt = 0; nt < 4; ++nt) {
            float e[4];
#pragma unroll
            for (int r = 0; r < 4; ++r) {
                float vv = __expf(s[nt][r] * SCALE);
                if (diag && (nt * 16 + lg * 4 + r > rloc)) vv = 0.f;
                e[r] = vv;
            }
            rsum += (e[0] + e[1]) + (e[2] + e[3]);
            const int colp = (nt * 16 + lg * 4) ^ sw;
            s4v pv = { f2bf(e[0]), f2bf(e[1]), f2bf(e[2]), f2bf(e[3]) };
            *reinterpret_cast<s4v*>(&Pl[w * 1024 + lr * 64 + colp]) = pv;
        }

        // PV: A = P[q=lane&15][j] (LDS b128), B = V^T rows (global 16B)
        s8v pf0 = *reinterpret_cast<const s8v*>(&Pl[w * 1024 + lr * 64 + ((lg * 8) ^ sw)]);
        s8v pf1 = *reinterpret_cast<const s8v*>(&Pl[w * 1024 + lr * 64 + ((32 + lg * 8) ^ sw)]);
#pragma unroll
        for (int nt = 0; nt < 4; ++nt) {
            const short* vr = vt + (size_t)(bh * 64 + nt * 16 + lr) * T_ + jc + lg * 8;
            s8v vf0 = *reinterpret_cast<const s8v*>(vr);
            s8v vf1 = *reinterpret_cast<const s8v*>(vr + 32);
            accO[nt] = MFMA16(pf0, vf0, accO[nt]);
            accO[nt] = MFMA16(pf1, vf1, accO[nt]);
        }
    }

    // in-wave rowsum combine: lanes lr,lr+16,lr+32,lr+48 hold disjoint j sets
    rsum += __shfl_xor(rsum, 16);
    rsum += __shfl_xor(rsum, 32);              // full partial for row lr

    __syncthreads();                            // all Pl reads done
    if (lg == 0) rsbuf[w * 16 + lr] = rsum;
#pragma unroll
    for (int nt = 0; nt < 4; ++nt)
        st4(&OA[(size_t)(w * 64 + l) * 16 + nt * 4], *(const float4*)&accO[nt]);
    __syncthreads();

    // cross-wave reduce: wave w produces out cols [w*16, w*16+16)
    float osum[4];
#pragma unroll
    for (int r = 0; r < 4; ++r) osum[r] = 0.f;
#pragma unroll
    for (int wv = 0; wv < 4; ++wv) {
        float4 p = *(const float4*)&OA[(size_t)(wv * 64 + l) * 16 + w * 4];
#pragma unroll
        for (int r = 0; r < 4; ++r) osum[r] += (&p.x)[r];
    }
#pragma unroll
    for (int r = 0; r < 4; ++r) {
        const int ro = lg * 4 + r;             // local row 0..15
        const float rt = rsbuf[ro] + rsbuf[16 + ro] + rsbuf[32 + ro] + rsbuf[48 + ro];
        out[(size_t)(b * T_ + g16 * 16 + ro) * NU_ + h * DH_ + w * 16 + lr] =
            osum[r] / rt;
    }
    if (w == 0 && t < 16)
        rsws[(size_t)bh * T_ + g16 * 16 + t] =
            rsbuf[t] + rsbuf[16 + t] + rsbuf[32 + t] + rsbuf[48 + t];
}

// ---------------------------------------------------------------------------
// Attention pass B (weights, causal blocks only): block = 64 q-rows x 256
// j-cols (4 chunks); early-exit blocks with no causal work (handled by
// attn_wts_fill). Reads rsws; recomputes swapped QK^T; cached st4 stores
// (L2 merges 64B segments; nt-stores caused 1.66x amplification in R6).
// grid 8192, 256 threads.
// ---------------------------------------------------------------------------
__global__ __launch_bounds__(256) void attn_wts_score(
    const short* __restrict__ qb, const short* __restrict__ kb,
    const float* __restrict__ rsws, float* __restrict__ wts)
{
    const int lin = blockIdx.x;
    const int xcd = lin & 7, v = lin >> 3;
    const int bh  = xcd * 4 + (v >> 8);
    const int qt  = 31 - ((v >> 3) & 31);      // heavy q-tiles first
    const int jb  = v & 7;
    if (jb * 4 > qt) return;                   // fully above diagonal -> fill kernel
    const int b = bh >> 4, h = bh & 15;
    const int r0 = qt * 64;
    const int t = threadIdx.x, w = t >> 6, l = t & 63;
    const int lr = l & 15, lg = l >> 4;

    const short* qrow = qb + (size_t)(b * T_ + r0 + w * 16 + lr) * NU_ + h * DH_ + lg * 8;
    const s8v qf0 = *reinterpret_cast<const s8v*>(qrow);
    const s8v qf1 = *reinterpret_cast<const s8v*>(qrow + 32);
    const f4 zf = (f4){0.f, 0.f, 0.f, 0.f};

    const int iRow = r0 + w * 16 + lr;          // this lane's q-row
    const float inv = 1.f / rsws[(size_t)bh * T_ + iRow];
    float* const wrow = &wts[((size_t)bh * T_ + iRow) * T_];
    const short* kbase0 = kb + (size_t)(b * T_) * NU_ + h * DH_ + lg * 8;

#pragma unroll
    for (int cx = 0; cx < 4; ++cx) {
        const int ch = jb * 4 + cx;
        const int jc = ch * 64;
        if (ch <= qt) {
            const bool diag = (ch == qt);
            f4 s[4];
            const short* kbase = kbase0 + (size_t)jc * NU_;
#pragma unroll
            for (int nt = 0; nt < 4; ++nt) {
                const short* kr = kbase + (size_t)(nt * 16 + lr) * NU_;
                s8v kf0 = *reinterpret_cast<const s8v*>(kr);
                s8v kf1 = *reinterpret_cast<const s8v*>(kr + 32);
                f4 a = MFMA16(kf0, qf0, zf);
                s[nt] = MFMA16(kf1, qf1, a);
            }
#pragma unroll
            for (int nt = 0; nt < 4; ++nt) {
                float4 o;
                float* e = &o.x;
#pragma unroll
                for (int r = 0; r < 4; ++r) {
                    float vv = __expf(s[nt][r] * SCALE) * inv;
                    if (diag && (nt * 16 + lg * 4 + r > w * 16 + lr)) vv = 0.f;
                    e[r] = vv;
                }
                st4(wrow + jc + nt * 16 + lg * 4, o);
            }
        } else {
            // partial zero chunk within a mixed block (diag straddles)
            float* dst = &wts[((size_t)bh * T_ + r0 + (t >> 2)) * T_ + jc + (t & 3) * 16];
            const float4 z4 = make_float4(0.f, 0.f, 0.f, 0.f);
            st4(dst + 0, z4); st4(dst + 4, z4); st4(dst + 8, z4); st4(dst + 12, z4);
        }
    }
}

// ---------------------------------------------------------------------------
extern "C" void kernel_launch(void* const* d_in, const int* in_sizes, int n_in,
                              void* d_out, int out_size, void* d_ws, size_t ws_size,
                              hipStream_t stream)
{
    const float* queries = (const float*)d_in[0];
    const float* keys    = (const float*)d_in[1];
    const float* Wq = (const float*)d_in[2];
    const float* bq = (const float*)d_in[3];
    const float* Wk = (const float*)d_in[4];
    const float* bk = (const float*)d_in[5];
    const float* Wv = (const float*)d_in[6];
    const float* bv = (const float*)d_in[7];

    float* out = (float*)d_out;                 // [B,T,NU]
    float* wts = out + OUT_ELEMS;               // [B,H,T,T]

    // workspace (bf16 shorts unless noted), total ~44.3 MB:
    short* qx = (short*)d_ws;                               // queries bf16 [4096][1024]
    short* kx = qx + (size_t)B_ * T_ * D_;                  // keys bf16
    short* wt = kx + (size_t)B_ * T_ * D_;                  // Wt bf16 [3][N][K]
    short* qb = wt + (size_t)3 * D_ * NU_;                  // q proj bf16 [4096][1024]
    short* kb = qb + (size_t)B_ * T_ * NU_;                 // k proj bf16
    short* vt = kb + (size_t)B_ * T_ * NU_;                 // v proj bf16, [bh][d][t]
    float* rsws = (float*)(vt + (size_t)B_ * T_ * NU_);     // rowsums [bh][t]

    cvt_x_kernel<<<dim3((B_ * T_ * D_) / 2048, 2), 256, 0, stream>>>(queries, keys, qx, kx);
    cvt_w_kernel<<<dim3(16, 16, 3), 256, 0, stream>>>(Wq, Wk, Wv, wt);
    attn_wts_fill<<<dim3(8192), 256, 0, stream>>>(wts);
    proj_mfma<<<dim3(8, 32, 3), 256, 0, stream>>>(
        qx, kx, wt, bq, bk, bv, qb, kb, vt);
    attn_pv_mfma<<<dim3(4096), 256, 0, stream>>>(qb, kb, vt, rsws, out);
    attn_wts_score<<<dim3(8192), 256, 0, stream>>>(qb, kb, rsws, wts);
}

// Round 10
// 306.670 us; speedup vs baseline: 1.3959x; 1.2006x over previous
//
#include <hip/hip_runtime.h>
#include <cstddef>
#include <cstdint>

// Problem constants (reference: B=2, T=2048, D=1024, H=16, DH=64, NU=1024)
namespace {
constexpr int B_ = 2, T_ = 2048, D_ = 1024, H_ = 16, DH_ = 64, NU_ = 1024;
constexpr float SCALE = 0.03125f;           // NU^-0.5 = 1/32
constexpr size_t OUT_ELEMS = (size_t)B_ * T_ * NU_;   // 4,194,304
}

using f4  = __attribute__((ext_vector_type(4))) float;
using s8v = __attribute__((ext_vector_type(8))) short;   // 8 bf16 (4 VGPRs)
using s4v = __attribute__((ext_vector_type(4))) short;

#define MFMA16(a, b, c) __builtin_amdgcn_mfma_f32_16x16x32_bf16((a), (b), (c), 0, 0, 0)

__device__ __forceinline__ float4 ld4(const float* p) { return *reinterpret_cast<const float4*>(p); }
__device__ __forceinline__ void st4(float* p, const float4 v) { *reinterpret_cast<float4*>(p) = v; }
__device__ __forceinline__ short f2bf(float f) {      // fp32 -> bf16 RNE
    union { float f; uint32_t u; } v{f};
    uint32_t r = (v.u + 0x7fffu + ((v.u >> 16) & 1u)) >> 16;
    return (short)r;
}

#if __has_builtin(__builtin_amdgcn_global_load_lds)
#define HAVE_GLOAD_LDS 1
__device__ __forceinline__ void load_lds16(const void* g, void* l) {
    __builtin_amdgcn_global_load_lds(
        (const __attribute__((address_space(1))) void*)g,
        (__attribute__((address_space(3))) void*)l, 16, 0, 0);
}
#else
#define HAVE_GLOAD_LDS 0
#endif

// ---------------------------------------------------------------------------
// Convert queries/keys fp32 -> bf16 row-major. grid (N/2048, 2).
// ---------------------------------------------------------------------------
__global__ __launch_bounds__(256) void cvt_x_kernel(
    const float* __restrict__ q, const float* __restrict__ k,
    short* __restrict__ qx, short* __restrict__ kx)
{
    const float* src = blockIdx.y ? k : q;
    short* dst       = blockIdx.y ? kx : qx;
    size_t i = ((size_t)blockIdx.x * 256 + threadIdx.x) * 8;
    float4 a = ld4(src + i), b = ld4(src + i + 4);
    s8v o = { f2bf(a.x), f2bf(a.y), f2bf(a.z), f2bf(a.w),
              f2bf(b.x), f2bf(b.y), f2bf(b.z), f2bf(b.w) };
    *reinterpret_cast<s8v*>(dst + i) = o;
}

// ---------------------------------------------------------------------------
// Convert + transpose W fp32 [K][N] -> bf16 Wt [N][K]. grid (16,16,3).
// ---------------------------------------------------------------------------
__global__ __launch_bounds__(256) void cvt_w_kernel(
    const float* __restrict__ Wq, const float* __restrict__ Wk,
    const float* __restrict__ Wv, short* __restrict__ wt3)
{
    const int z = blockIdx.z;
    const float* W = (z == 0) ? Wq : (z == 1) ? Wk : Wv;
    short* dst = wt3 + (size_t)z * D_ * NU_;
    const int n0 = blockIdx.x * 64, k0 = blockIdx.y * 64;
    __shared__ float tl[64][68];
    const int rr = threadIdx.x >> 2, cc = (threadIdx.x & 3) * 16;
    const float* s = W + (size_t)(k0 + rr) * NU_ + n0 + cc;
    st4(&tl[rr][cc + 0],  ld4(s + 0));
    st4(&tl[rr][cc + 4],  ld4(s + 4));
    st4(&tl[rr][cc + 8],  ld4(s + 8));
    st4(&tl[rr][cc + 12], ld4(s + 12));
    __syncthreads();
    short* d = dst + (size_t)(n0 + rr) * D_ + k0 + cc;
#pragma unroll
    for (int c = 0; c < 4; ++c) {
        s4v o = { f2bf(tl[cc + c * 4 + 0][rr]), f2bf(tl[cc + c * 4 + 1][rr]),
                  f2bf(tl[cc + c * 4 + 2][rr]), f2bf(tl[cc + c * 4 + 3][rr]) };
        *reinterpret_cast<s4v*>(d + c * 4) = o;
    }
}

// ---------------------------------------------------------------------------
// QKV projection, bf16 MFMA: 128x128 tile, BK=64, 4 waves, global_load_lds
// width-16 into linear [128][64] LDS. XCD-chunked remap (768 = 8 x 96).
// z=0->qb, z=1->kb, z=2->vt ([bh][d][t] transposed). grid(8,32,3), 256 thr.
// ---------------------------------------------------------------------------
__global__ __launch_bounds__(256) void proj_mfma(
    const short* __restrict__ qx, const short* __restrict__ kx,
    const short* __restrict__ wt3,
    const float* __restrict__ bq, const float* __restrict__ bk,
    const float* __restrict__ bv,
    short* __restrict__ qb, short* __restrict__ kb, short* __restrict__ vt)
{
    const int lin = blockIdx.z * 256 + blockIdx.y * 8 + blockIdx.x;
    const int virt = (lin & 7) * 96 + (lin >> 3);
    const int z = virt >> 8, rem = virt & 255;
    const int m0 = (rem >> 3) * 128, n0 = (rem & 7) * 128;

    const short* __restrict__ X  = (z == 0) ? qx : kx;
    const short* __restrict__ Wt = wt3 + (size_t)z * D_ * NU_;
    const float* __restrict__ bias = (z == 0) ? bq : (z == 1) ? bk : bv;

    const int t = threadIdx.x, w = t >> 6, l = t & 63;
    const int lr = l & 15, lg = l >> 4;
    const int wr = w >> 1, wc = w & 1;

    __shared__ short Asl[128 * 64];   // [row][k] linear, 16KB
    __shared__ short Bsl[128 * 64];   // [n][k] linear, 16KB

    f4 acc[4][4];
#pragma unroll
    for (int m = 0; m < 4; ++m)
#pragma unroll
        for (int n = 0; n < 4; ++n) acc[m][n] = (f4){0.f, 0.f, 0.f, 0.f};

    for (int k0 = 0; k0 < D_; k0 += 64) {
#if HAVE_GLOAD_LDS
#pragma unroll
        for (int j = 0; j < 4; ++j) {
            const int c0 = (w * 4 + j) * 64;
            const int c  = c0 + l;
            const int row = c >> 3, qo = (c & 7) * 8;
            load_lds16(X  + (size_t)(m0 + row) * D_ + k0 + qo, (char*)Asl + (size_t)c0 * 16);
            load_lds16(Wt + (size_t)(n0 + row) * D_ + k0 + qo, (char*)Bsl + (size_t)c0 * 16);
        }
        __syncthreads();
#else
        {
            const int sr = t >> 1, sc = (t & 1) * 32;
            s8v a0 = *reinterpret_cast<const s8v*>(X  + (size_t)(m0 + sr) * D_ + k0 + sc);
            s8v a1 = *reinterpret_cast<const s8v*>(X  + (size_t)(m0 + sr) * D_ + k0 + sc + 8);
            s8v a2 = *reinterpret_cast<const s8v*>(X  + (size_t)(m0 + sr) * D_ + k0 + sc + 16);
            s8v a3 = *reinterpret_cast<const s8v*>(X  + (size_t)(m0 + sr) * D_ + k0 + sc + 24);
            s8v b0 = *reinterpret_cast<const s8v*>(Wt + (size_t)(n0 + sr) * D_ + k0 + sc);
            s8v b1 = *reinterpret_cast<const s8v*>(Wt + (size_t)(n0 + sr) * D_ + k0 + sc + 8);
            s8v b2 = *reinterpret_cast<const s8v*>(Wt + (size_t)(n0 + sr) * D_ + k0 + sc + 16);
            s8v b3 = *reinterpret_cast<const s8v*>(Wt + (size_t)(n0 + sr) * D_ + k0 + sc + 24);
            __syncthreads();
            *reinterpret_cast<s8v*>(&Asl[sr * 64 + sc])      = a0;
            *reinterpret_cast<s8v*>(&Asl[sr * 64 + sc + 8])  = a1;
            *reinterpret_cast<s8v*>(&Asl[sr * 64 + sc + 16]) = a2;
            *reinterpret_cast<s8v*>(&Asl[sr * 64 + sc + 24]) = a3;
            *reinterpret_cast<s8v*>(&Bsl[sr * 64 + sc])      = b0;
            *reinterpret_cast<s8v*>(&Bsl[sr * 64 + sc + 8])  = b1;
            *reinterpret_cast<s8v*>(&Bsl[sr * 64 + sc + 16]) = b2;
            *reinterpret_cast<s8v*>(&Bsl[sr * 64 + sc + 24]) = b3;
            __syncthreads();
        }
#endif

#pragma unroll
        for (int kk = 0; kk < 2; ++kk) {
            s8v af[4], bf[4];
#pragma unroll
            for (int m = 0; m < 4; ++m)
                af[m] = *reinterpret_cast<const s8v*>(
                    &Asl[(wr * 64 + m * 16 + lr) * 64 + kk * 32 + lg * 8]);
#pragma unroll
            for (int n = 0; n < 4; ++n)
                bf[n] = *reinterpret_cast<const s8v*>(
                    &Bsl[(wc * 64 + n * 16 + lr) * 64 + kk * 32 + lg * 8]);
#pragma unroll
            for (int m = 0; m < 4; ++m)
#pragma unroll
                for (int n = 0; n < 4; ++n)
                    acc[m][n] = MFMA16(af[m], bf[n], acc[m][n]);
        }
        __syncthreads();
    }

    if (z < 2) {
        short* __restrict__ Y = (z == 0) ? qb : kb;
#pragma unroll
        for (int n = 0; n < 4; ++n) {
            const int col = n0 + wc * 64 + n * 16 + lr;
            const float bval = bias[col];
#pragma unroll
            for (int m = 0; m < 4; ++m) {
                const int row0 = m0 + wr * 64 + m * 16 + lg * 4;
#pragma unroll
                for (int r = 0; r < 4; ++r)
                    Y[(size_t)(row0 + r) * NU_ + col] = f2bf(acc[m][n][r] + bval);
            }
        }
    } else {
#pragma unroll
        for (int n = 0; n < 4; ++n) {
            const int col = n0 + wc * 64 + n * 16 + lr;   // 0..1023
            const float bval = bias[col];
            const int hh = col >> 6, dd = col & 63;
#pragma unroll
            for (int m = 0; m < 4; ++m) {
                const int Mi = m0 + wr * 64 + m * 16 + lg * 4;
                const int bb = Mi >> 11, t0 = Mi & 2047;
                s4v o = { f2bf(acc[m][n][0] + bval), f2bf(acc[m][n][1] + bval),
                          f2bf(acc[m][n][2] + bval), f2bf(acc[m][n][3] + bval) };
                *reinterpret_cast<s4v*>(vt + ((size_t)(bb * 16 + hh) * 64 + dd) * T_ + t0) = o;
            }
        }
    }
}

// ---------------------------------------------------------------------------
// Attention pass A (PV + rowsums + out), 32-row blocks: two 16-row bands
// (A/B) share every K/V fragment — loads per output row halve, per-chunk
// ILP doubles (2 independent QK chains + 2 PV chains per nt). Waves still
// split the chunk range (w, w+4, ...). P buffers: per-band per-wave LDS
// regions (barrier-free loop, in-order DS within wave). Epilogue reduces
// band A then band B over the same aliased 16KB OA buffer.
// grid 2048, 256 threads. XCD-chunked; heavy bands first.
// ---------------------------------------------------------------------------
__global__ __launch_bounds__(256) void attn_pv_mfma(
    const short* __restrict__ qb, const short* __restrict__ kb,
    const short* __restrict__ vt, float* __restrict__ rsws,
    float* __restrict__ out)
{
    const int lin = blockIdx.x;
    const int xcd = lin & 7, v = lin >> 3;     // v: 0..255
    const int bh  = xcd * 4 + (v >> 6);
    const int g32 = 63 - (v & 63);             // heavy 32-row bands first
    const int b = bh >> 4, h = bh & 15;
    const int r0 = g32 * 32;
    const int t = threadIdx.x, w = t >> 6, l = t & 63;
    const int lr = l & 15, lg = l >> 4;
    const int tile16 = (r0 + 31) >> 6;         // diagonal chunk index
    const int rlocA  = r0 - tile16 * 64 + lr;  // band-A row pos in diag chunk
    // band-B pos = rlocA + 16

    __shared__ __align__(16) char smem[16 * 1024 + 512];
    short* Pl    = (short*)smem;               // [band][wave][16][64] bf16, 16KB
    float* OA    = (float*)smem;               // 4x64x16 f32 (aliased after barrier)
    float* rsbuf = (float*)(smem + 16 * 1024); // [band][64]

    // Q fragments for both bands (B-operand: col=lane&15=q-row)
    const short* qrowA = qb + (size_t)(b * T_ + r0 + lr) * NU_ + h * DH_ + lg * 8;
    const s8v qA0 = *reinterpret_cast<const s8v*>(qrowA);
    const s8v qA1 = *reinterpret_cast<const s8v*>(qrowA + 32);
    const s8v qB0 = *reinterpret_cast<const s8v*>(qrowA + 16 * NU_);
    const s8v qB1 = *reinterpret_cast<const s8v*>(qrowA + 16 * NU_ + 32);

    f4 accA[4], accB[4];
#pragma unroll
    for (int nt = 0; nt < 4; ++nt) {
        accA[nt] = (f4){0.f, 0.f, 0.f, 0.f};
        accB[nt] = (f4){0.f, 0.f, 0.f, 0.f};
    }
    float rsumA = 0.f, rsumB = 0.f;
    const f4 zf = (f4){0.f, 0.f, 0.f, 0.f};
    const int sw = (lr & 7) << 3;              // P swizzle keyed on q-row
    const short* kbase0 = kb + (size_t)(b * T_) * NU_ + h * DH_ + lg * 8;
    short* const PlA = &Pl[w * 1024 + lr * 64];
    short* const PlB = &Pl[4096 + w * 1024 + lr * 64];

    for (int ch = w; ch <= tile16; ch += 4) {
        const int jc = ch * 64;
        const bool diag = (ch == tile16);
        const short* kbase = kbase0 + (size_t)jc * NU_;

        // ---- swapped QK^T, both bands share kf ----
#pragma unroll
        for (int nt = 0; nt < 4; ++nt) {
            const short* kr = kbase + (size_t)(nt * 16 + lr) * NU_;
            s8v kf0 = *reinterpret_cast<const s8v*>(kr);
            s8v kf1 = *reinterpret_cast<const s8v*>(kr + 32);
            f4 aA = MFMA16(kf0, qA0, zf);
            f4 sA = MFMA16(kf1, qA1, aA);
            f4 aB = MFMA16(kf0, qB0, zf);
            f4 sB = MFMA16(kf1, qB1, aB);

            const int jl = nt * 16 + lg * 4;   // lane's j base this nt
            float eA[4], eB[4];
#pragma unroll
            for (int r = 0; r < 4; ++r) {
                float vA = __expf(sA[r] * SCALE);
                float vB = __expf(sB[r] * SCALE);
                if (diag && (jl + r > rlocA))      vA = 0.f;
                if (diag && (jl + r > rlocA + 16)) vB = 0.f;
                eA[r] = vA; eB[r] = vB;
            }
            rsumA += (eA[0] + eA[1]) + (eA[2] + eA[3]);
            rsumB += (eB[0] + eB[1]) + (eB[2] + eB[3]);
            const int colp = jl ^ sw;
            s4v pA = { f2bf(eA[0]), f2bf(eA[1]), f2bf(eA[2]), f2bf(eA[3]) };
            s4v pB = { f2bf(eB[0]), f2bf(eB[1]), f2bf(eB[2]), f2bf(eB[3]) };
            *reinterpret_cast<s4v*>(PlA + colp) = pA;
            *reinterpret_cast<s4v*>(PlB + colp) = pB;
        }

        // ---- PV: both bands share vf ----
        s8v pfA0 = *reinterpret_cast<const s8v*>(PlA + ((lg * 8) ^ sw));
        s8v pfA1 = *reinterpret_cast<const s8v*>(PlA + ((32 + lg * 8) ^ sw));
        s8v pfB0 = *reinterpret_cast<const s8v*>(PlB + ((lg * 8) ^ sw));
        s8v pfB1 = *reinterpret_cast<const s8v*>(PlB + ((32 + lg * 8) ^ sw));
#pragma unroll
        for (int nt = 0; nt < 4; ++nt) {
            const short* vr = vt + (size_t)(bh * 64 + nt * 16 + lr) * T_ + jc + lg * 8;
            s8v vf0 = *reinterpret_cast<const s8v*>(vr);
            s8v vf1 = *reinterpret_cast<const s8v*>(vr + 32);
            accA[nt] = MFMA16(pfA0, vf0, accA[nt]);
            accA[nt] = MFMA16(pfA1, vf1, accA[nt]);
            accB[nt] = MFMA16(pfB0, vf0, accB[nt]);
            accB[nt] = MFMA16(pfB1, vf1, accB[nt]);
        }
    }

    // in-wave rowsum combine (lanes lr,lr+16,... hold disjoint j sets)
    rsumA += __shfl_xor(rsumA, 16); rsumA += __shfl_xor(rsumA, 32);
    rsumB += __shfl_xor(rsumB, 16); rsumB += __shfl_xor(rsumB, 32);

    __syncthreads();                            // all Pl reads done (OA alias)
    if (lg == 0) {
        rsbuf[w * 16 + lr]      = rsumA;
        rsbuf[64 + w * 16 + lr] = rsumB;
    }

    // ---- band A reduce + store ----
#pragma unroll
    for (int nt = 0; nt < 4; ++nt)
        st4(&OA[(size_t)(w * 64 + l) * 16 + nt * 4], *(const float4*)&accA[nt]);
    __syncthreads();
    {
        float osum[4] = {0.f, 0.f, 0.f, 0.f};
#pragma unroll
        for (int wv = 0; wv < 4; ++wv) {
            float4 p = *(const float4*)&OA[(size_t)(wv * 64 + l) * 16 + w * 4];
#pragma unroll
            for (int r = 0; r < 4; ++r) osum[r] += (&p.x)[r];
        }
#pragma unroll
        for (int r = 0; r < 4; ++r) {
            const int ro = lg * 4 + r;
            const float rt = rsbuf[ro] + rsbuf[16 + ro] + rsbuf[32 + ro] + rsbuf[48 + ro];
            out[(size_t)(b * T_ + r0 + ro) * NU_ + h * DH_ + w * 16 + lr] = osum[r] / rt;
        }
        if (w == 0 && t < 16) {
            rsws[(size_t)bh * T_ + r0 + t] =
                rsbuf[t] + rsbuf[16 + t] + rsbuf[32 + t] + rsbuf[48 + t];
            rsws[(size_t)bh * T_ + r0 + 16 + t] =
                rsbuf[64 + t] + rsbuf[80 + t] + rsbuf[96 + t] + rsbuf[112 + t];
        }
    }
    __syncthreads();                            // band-A OA reads done

    // ---- band B reduce + store (reuse OA) ----
#pragma unroll
    for (int nt = 0; nt < 4; ++nt)
        st4(&OA[(size_t)(w * 64 + l) * 16 + nt * 4], *(const float4*)&accB[nt]);
    __syncthreads();
    {
        float osum[4] = {0.f, 0.f, 0.f, 0.f};
#pragma unroll
        for (int wv = 0; wv < 4; ++wv) {
            float4 p = *(const float4*)&OA[(size_t)(wv * 64 + l) * 16 + w * 4];
#pragma unroll
            for (int r = 0; r < 4; ++r) osum[r] += (&p.x)[r];
        }
#pragma unroll
        for (int r = 0; r < 4; ++r) {
            const int ro = lg * 4 + r;
            const float rt = rsbuf[64 + ro] + rsbuf[80 + ro] + rsbuf[96 + ro] + rsbuf[112 + ro];
            out[(size_t)(b * T_ + r0 + 16 + ro) * NU_ + h * DH_ + w * 16 + lr] = osum[r] / rt;
        }
    }
}

// ---------------------------------------------------------------------------
// Attention pass B (weights): block = 64 q-rows x 256 j-cols (4 chunks).
// Combined score + zero-fill in ONE kernel (R9 split lost intra-dispatch
// overlap, -14us). Cached st4 stores (nt-stores amplified 1.66x, R6).
// grid 8192, 256 threads.
// ---------------------------------------------------------------------------
__global__ __launch_bounds__(256) void attn_wts_mfma(
    const short* __restrict__ qb, const short* __restrict__ kb,
    const float* __restrict__ rsws, float* __restrict__ wts)
{
    const int lin = blockIdx.x;
    const int xcd = lin & 7, v = lin >> 3;
    const int bh  = xcd * 4 + (v >> 8);
    const int qt  = 31 - ((v >> 3) & 31);      // heavy q-tiles first
    const int jb  = v & 7;
    const int b = bh >> 4, h = bh & 15;
    const int r0 = qt * 64;
    const int t = threadIdx.x, w = t >> 6, l = t & 63;
    const int lr = l & 15, lg = l >> 4;

    const short* qrow = qb + (size_t)(b * T_ + r0 + w * 16 + lr) * NU_ + h * DH_ + lg * 8;
    const s8v qf0 = *reinterpret_cast<const s8v*>(qrow);
    const s8v qf1 = *reinterpret_cast<const s8v*>(qrow + 32);
    const f4 zf = (f4){0.f, 0.f, 0.f, 0.f};

    const int iRow = r0 + w * 16 + lr;          // this lane's q-row
    const float inv = 1.f / rsws[(size_t)bh * T_ + iRow];
    float* const wrow = &wts[((size_t)bh * T_ + iRow) * T_];
    const short* kbase0 = kb + (size_t)(b * T_) * NU_ + h * DH_ + lg * 8;

#pragma unroll
    for (int cx = 0; cx < 4; ++cx) {
        const int ch = jb * 4 + cx;
        const int jc = ch * 64;
        if (ch <= qt) {
            const bool diag = (ch == qt);
            f4 s[4];
            const short* kbase = kbase0 + (size_t)jc * NU_;
#pragma unroll
            for (int nt = 0; nt < 4; ++nt) {
                const short* kr = kbase + (size_t)(nt * 16 + lr) * NU_;
                s8v kf0 = *reinterpret_cast<const s8v*>(kr);
                s8v kf1 = *reinterpret_cast<const s8v*>(kr + 32);
                f4 a = MFMA16(kf0, qf0, zf);
                s[nt] = MFMA16(kf1, qf1, a);
            }
#pragma unroll
            for (int nt = 0; nt < 4; ++nt) {
                float4 o;
                float* e = &o.x;
#pragma unroll
                for (int r = 0; r < 4; ++r) {
                    float vv = __expf(s[nt][r] * SCALE) * inv;
                    if (diag && (nt * 16 + lg * 4 + r > w * 16 + lr)) vv = 0.f;
                    e[r] = vv;
                }
                st4(wrow + jc + nt * 16 + lg * 4, o);
            }
        } else {
            // fully above the diagonal: block covers 64 rows x 64 cols
            float* dst = &wts[((size_t)bh * T_ + r0 + (t >> 2)) * T_ + jc + (t & 3) * 16];
            const float4 z4 = make_float4(0.f, 0.f, 0.f, 0.f);
            st4(dst + 0, z4); st4(dst + 4, z4); st4(dst + 8, z4); st4(dst + 12, z4);
        }
    }
}

// ---------------------------------------------------------------------------
extern "C" void kernel_launch(void* const* d_in, const int* in_sizes, int n_in,
                              void* d_out, int out_size, void* d_ws, size_t ws_size,
                              hipStream_t stream)
{
    const float* queries = (const float*)d_in[0];
    const float* keys    = (const float*)d_in[1];
    const float* Wq = (const float*)d_in[2];
    const float* bq = (const float*)d_in[3];
    const float* Wk = (const float*)d_in[4];
    const float* bk = (const float*)d_in[5];
    const float* Wv = (const float*)d_in[6];
    const float* bv = (const float*)d_in[7];

    float* out = (float*)d_out;                 // [B,T,NU]
    float* wts = out + OUT_ELEMS;               // [B,H,T,T]

    // workspace (bf16 shorts unless noted), total ~44.3 MB:
    short* qx = (short*)d_ws;                               // queries bf16 [4096][1024]
    short* kx = qx + (size_t)B_ * T_ * D_;                  // keys bf16
    short* wt = kx + (size_t)B_ * T_ * D_;                  // Wt bf16 [3][N][K]
    short* qb = wt + (size_t)3 * D_ * NU_;                  // q proj bf16 [4096][1024]
    short* kb = qb + (size_t)B_ * T_ * NU_;                 // k proj bf16
    short* vt = kb + (size_t)B_ * T_ * NU_;                 // v proj bf16, [bh][d][t]
    float* rsws = (float*)(vt + (size_t)B_ * T_ * NU_);     // rowsums [bh][t]

    cvt_x_kernel<<<dim3((B_ * T_ * D_) / 2048, 2), 256, 0, stream>>>(queries, keys, qx, kx);
    cvt_w_kernel<<<dim3(16, 16, 3), 256, 0, stream>>>(Wq, Wk, Wv, wt);
    proj_mfma<<<dim3(8, 32, 3), 256, 0, stream>>>(
        qx, kx, wt, bq, bk, bv, qb, kb, vt);
    attn_pv_mfma<<<dim3(2048), 256, 0, stream>>>(qb, kb, vt, rsws, out);
    attn_wts_mfma<<<dim3(8192), 256, 0, stream>>>(qb, kb, rsws, wts);
}

// Round 11
// 295.604 us; speedup vs baseline: 1.4481x; 1.0374x over previous
//
#include <hip/hip_runtime.h>
#include <cstddef>
#include <cstdint>

// Problem constants (reference: B=2, T=2048, D=1024, H=16, DH=64, NU=1024)
namespace {
constexpr int B_ = 2, T_ = 2048, D_ = 1024, H_ = 16, DH_ = 64, NU_ = 1024;
constexpr float SCALE = 0.03125f;           // NU^-0.5 = 1/32
constexpr size_t OUT_ELEMS = (size_t)B_ * T_ * NU_;   // 4,194,304
}

using f4  = __attribute__((ext_vector_type(4))) float;
using s8v = __attribute__((ext_vector_type(8))) short;   // 8 bf16 (4 VGPRs)
using s4v = __attribute__((ext_vector_type(4))) short;

#define MFMA16(a, b, c) __builtin_amdgcn_mfma_f32_16x16x32_bf16((a), (b), (c), 0, 0, 0)

__device__ __forceinline__ float4 ld4(const float* p) { return *reinterpret_cast<const float4*>(p); }
__device__ __forceinline__ void st4(float* p, const float4 v) { *reinterpret_cast<float4*>(p) = v; }
__device__ __forceinline__ short f2bf(float f) {      // fp32 -> bf16 RNE
    union { float f; uint32_t u; } v{f};
    uint32_t r = (v.u + 0x7fffu + ((v.u >> 16) & 1u)) >> 16;
    return (short)r;
}

#if __has_builtin(__builtin_amdgcn_global_load_lds)
#define HAVE_GLOAD_LDS 1
__device__ __forceinline__ void load_lds16(const void* g, void* l) {
    __builtin_amdgcn_global_load_lds(
        (const __attribute__((address_space(1))) void*)g,
        (__attribute__((address_space(3))) void*)l, 16, 0, 0);
}
#else
#define HAVE_GLOAD_LDS 0
#endif

// ---------------------------------------------------------------------------
// Convert queries/keys fp32 -> bf16 row-major. grid (N/2048, 2).
// ---------------------------------------------------------------------------
__global__ __launch_bounds__(256) void cvt_x_kernel(
    const float* __restrict__ q, const float* __restrict__ k,
    short* __restrict__ qx, short* __restrict__ kx)
{
    const float* src = blockIdx.y ? k : q;
    short* dst       = blockIdx.y ? kx : qx;
    size_t i = ((size_t)blockIdx.x * 256 + threadIdx.x) * 8;
    float4 a = ld4(src + i), b = ld4(src + i + 4);
    s8v o = { f2bf(a.x), f2bf(a.y), f2bf(a.z), f2bf(a.w),
              f2bf(b.x), f2bf(b.y), f2bf(b.z), f2bf(b.w) };
    *reinterpret_cast<s8v*>(dst + i) = o;
}

// ---------------------------------------------------------------------------
// Convert + transpose W fp32 [K][N] -> bf16 Wt [N][K]. grid (16,16,3).
// ---------------------------------------------------------------------------
__global__ __launch_bounds__(256) void cvt_w_kernel(
    const float* __restrict__ Wq, const float* __restrict__ Wk,
    const float* __restrict__ Wv, short* __restrict__ wt3)
{
    const int z = blockIdx.z;
    const float* W = (z == 0) ? Wq : (z == 1) ? Wk : Wv;
    short* dst = wt3 + (size_t)z * D_ * NU_;
    const int n0 = blockIdx.x * 64, k0 = blockIdx.y * 64;
    __shared__ float tl[64][68];
    const int rr = threadIdx.x >> 2, cc = (threadIdx.x & 3) * 16;
    const float* s = W + (size_t)(k0 + rr) * NU_ + n0 + cc;
    st4(&tl[rr][cc + 0],  ld4(s + 0));
    st4(&tl[rr][cc + 4],  ld4(s + 4));
    st4(&tl[rr][cc + 8],  ld4(s + 8));
    st4(&tl[rr][cc + 12], ld4(s + 12));
    __syncthreads();
    short* d = dst + (size_t)(n0 + rr) * D_ + k0 + cc;
#pragma unroll
    for (int c = 0; c < 4; ++c) {
        s4v o = { f2bf(tl[cc + c * 4 + 0][rr]), f2bf(tl[cc + c * 4 + 1][rr]),
                  f2bf(tl[cc + c * 4 + 2][rr]), f2bf(tl[cc + c * 4 + 3][rr]) };
        *reinterpret_cast<s4v*>(d + c * 4) = o;
    }
}

// ---------------------------------------------------------------------------
// QKV projection, bf16 MFMA: 128x128 tile, BK=64, 4 waves, global_load_lds
// width-16 into linear [128][64] LDS. XCD-chunked remap (768 = 8 x 96).
// z=0->qb, z=1->kb, z=2->vt ([bh][d][t] transposed). grid(8,32,3), 256 thr.
// ---------------------------------------------------------------------------
__global__ __launch_bounds__(256) void proj_mfma(
    const short* __restrict__ qx, const short* __restrict__ kx,
    const short* __restrict__ wt3,
    const float* __restrict__ bq, const float* __restrict__ bk,
    const float* __restrict__ bv,
    short* __restrict__ qb, short* __restrict__ kb, short* __restrict__ vt)
{
    const int lin = blockIdx.z * 256 + blockIdx.y * 8 + blockIdx.x;
    const int virt = (lin & 7) * 96 + (lin >> 3);
    const int z = virt >> 8, rem = virt & 255;
    const int m0 = (rem >> 3) * 128, n0 = (rem & 7) * 128;

    const short* __restrict__ X  = (z == 0) ? qx : kx;
    const short* __restrict__ Wt = wt3 + (size_t)z * D_ * NU_;
    const float* __restrict__ bias = (z == 0) ? bq : (z == 1) ? bk : bv;

    const int t = threadIdx.x, w = t >> 6, l = t & 63;
    const int lr = l & 15, lg = l >> 4;
    const int wr = w >> 1, wc = w & 1;

    __shared__ short Asl[128 * 64];   // [row][k] linear, 16KB
    __shared__ short Bsl[128 * 64];   // [n][k] linear, 16KB

    f4 acc[4][4];
#pragma unroll
    for (int m = 0; m < 4; ++m)
#pragma unroll
        for (int n = 0; n < 4; ++n) acc[m][n] = (f4){0.f, 0.f, 0.f, 0.f};

    for (int k0 = 0; k0 < D_; k0 += 64) {
#if HAVE_GLOAD_LDS
#pragma unroll
        for (int j = 0; j < 4; ++j) {
            const int c0 = (w * 4 + j) * 64;
            const int c  = c0 + l;
            const int row = c >> 3, qo = (c & 7) * 8;
            load_lds16(X  + (size_t)(m0 + row) * D_ + k0 + qo, (char*)Asl + (size_t)c0 * 16);
            load_lds16(Wt + (size_t)(n0 + row) * D_ + k0 + qo, (char*)Bsl + (size_t)c0 * 16);
        }
        __syncthreads();
#else
        {
            const int sr = t >> 1, sc = (t & 1) * 32;
            s8v a0 = *reinterpret_cast<const s8v*>(X  + (size_t)(m0 + sr) * D_ + k0 + sc);
            s8v a1 = *reinterpret_cast<const s8v*>(X  + (size_t)(m0 + sr) * D_ + k0 + sc + 8);
            s8v a2 = *reinterpret_cast<const s8v*>(X  + (size_t)(m0 + sr) * D_ + k0 + sc + 16);
            s8v a3 = *reinterpret_cast<const s8v*>(X  + (size_t)(m0 + sr) * D_ + k0 + sc + 24);
            s8v b0 = *reinterpret_cast<const s8v*>(Wt + (size_t)(n0 + sr) * D_ + k0 + sc);
            s8v b1 = *reinterpret_cast<const s8v*>(Wt + (size_t)(n0 + sr) * D_ + k0 + sc + 8);
            s8v b2 = *reinterpret_cast<const s8v*>(Wt + (size_t)(n0 + sr) * D_ + k0 + sc + 16);
            s8v b3 = *reinterpret_cast<const s8v*>(Wt + (size_t)(n0 + sr) * D_ + k0 + sc + 24);
            __syncthreads();
            *reinterpret_cast<s8v*>(&Asl[sr * 64 + sc])      = a0;
            *reinterpret_cast<s8v*>(&Asl[sr * 64 + sc + 8])  = a1;
            *reinterpret_cast<s8v*>(&Asl[sr * 64 + sc + 16]) = a2;
            *reinterpret_cast<s8v*>(&Asl[sr * 64 + sc + 24]) = a3;
            *reinterpret_cast<s8v*>(&Bsl[sr * 64 + sc])      = b0;
            *reinterpret_cast<s8v*>(&Bsl[sr * 64 + sc + 8])  = b1;
            *reinterpret_cast<s8v*>(&Bsl[sr * 64 + sc + 16]) = b2;
            *reinterpret_cast<s8v*>(&Bsl[sr * 64 + sc + 24]) = b3;
            __syncthreads();
        }
#endif

#pragma unroll
        for (int kk = 0; kk < 2; ++kk) {
            s8v af[4], bf[4];
#pragma unroll
            for (int m = 0; m < 4; ++m)
                af[m] = *reinterpret_cast<const s8v*>(
                    &Asl[(wr * 64 + m * 16 + lr) * 64 + kk * 32 + lg * 8]);
#pragma unroll
            for (int n = 0; n < 4; ++n)
                bf[n] = *reinterpret_cast<const s8v*>(
                    &Bsl[(wc * 64 + n * 16 + lr) * 64 + kk * 32 + lg * 8]);
#pragma unroll
            for (int m = 0; m < 4; ++m)
#pragma unroll
                for (int n = 0; n < 4; ++n)
                    acc[m][n] = MFMA16(af[m], bf[n], acc[m][n]);
        }
        __syncthreads();
    }

    if (z < 2) {
        short* __restrict__ Y = (z == 0) ? qb : kb;
#pragma unroll
        for (int n = 0; n < 4; ++n) {
            const int col = n0 + wc * 64 + n * 16 + lr;
            const float bval = bias[col];
#pragma unroll
            for (int m = 0; m < 4; ++m) {
                const int row0 = m0 + wr * 64 + m * 16 + lg * 4;
#pragma unroll
                for (int r = 0; r < 4; ++r)
                    Y[(size_t)(row0 + r) * NU_ + col] = f2bf(acc[m][n][r] + bval);
            }
        }
    } else {
#pragma unroll
        for (int n = 0; n < 4; ++n) {
            const int col = n0 + wc * 64 + n * 16 + lr;   // 0..1023
            const float bval = bias[col];
            const int hh = col >> 6, dd = col & 63;
#pragma unroll
            for (int m = 0; m < 4; ++m) {
                const int Mi = m0 + wr * 64 + m * 16 + lg * 4;
                const int bb = Mi >> 11, t0 = Mi & 2047;
                s4v o = { f2bf(acc[m][n][0] + bval), f2bf(acc[m][n][1] + bval),
                          f2bf(acc[m][n][2] + bval), f2bf(acc[m][n][3] + bval) };
                *reinterpret_cast<s4v*>(vt + ((size_t)(bb * 16 + hh) * 64 + dd) * T_ + t0) = o;
            }
        }
    }
}

// ---------------------------------------------------------------------------
// Attention pass A (PV + rowsums + out), 32-row blocks: two 16-row bands
// (A/B) share every K/V fragment (R10 structure, -48us vs 16-row).
// grid 2048, 256 threads. XCD-chunked; heavy bands first.
// ---------------------------------------------------------------------------
__global__ __launch_bounds__(256) void attn_pv_mfma(
    const short* __restrict__ qb, const short* __restrict__ kb,
    const short* __restrict__ vt, float* __restrict__ rsws,
    float* __restrict__ out)
{
    const int lin = blockIdx.x;
    const int xcd = lin & 7, v = lin >> 3;     // v: 0..255
    const int bh  = xcd * 4 + (v >> 6);
    const int g32 = 63 - (v & 63);             // heavy 32-row bands first
    const int b = bh >> 4, h = bh & 15;
    const int r0 = g32 * 32;
    const int t = threadIdx.x, w = t >> 6, l = t & 63;
    const int lr = l & 15, lg = l >> 4;
    const int tile16 = (r0 + 31) >> 6;         // diagonal chunk index
    const int rlocA  = r0 - tile16 * 64 + lr;  // band-A row pos in diag chunk

    __shared__ __align__(16) char smem[16 * 1024 + 512];
    short* Pl    = (short*)smem;               // [band][wave][16][64] bf16, 16KB
    float* OA    = (float*)smem;               // 4x64x16 f32 (aliased after barrier)
    float* rsbuf = (float*)(smem + 16 * 1024); // [band][64]

    const short* qrowA = qb + (size_t)(b * T_ + r0 + lr) * NU_ + h * DH_ + lg * 8;
    const s8v qA0 = *reinterpret_cast<const s8v*>(qrowA);
    const s8v qA1 = *reinterpret_cast<const s8v*>(qrowA + 32);
    const s8v qB0 = *reinterpret_cast<const s8v*>(qrowA + 16 * NU_);
    const s8v qB1 = *reinterpret_cast<const s8v*>(qrowA + 16 * NU_ + 32);

    f4 accA[4], accB[4];
#pragma unroll
    for (int nt = 0; nt < 4; ++nt) {
        accA[nt] = (f4){0.f, 0.f, 0.f, 0.f};
        accB[nt] = (f4){0.f, 0.f, 0.f, 0.f};
    }
    float rsumA = 0.f, rsumB = 0.f;
    const f4 zf = (f4){0.f, 0.f, 0.f, 0.f};
    const int sw = (lr & 7) << 3;              // P swizzle keyed on q-row
    const short* kbase0 = kb + (size_t)(b * T_) * NU_ + h * DH_ + lg * 8;
    short* const PlA = &Pl[w * 1024 + lr * 64];
    short* const PlB = &Pl[4096 + w * 1024 + lr * 64];

    for (int ch = w; ch <= tile16; ch += 4) {
        const int jc = ch * 64;
        const bool diag = (ch == tile16);
        const short* kbase = kbase0 + (size_t)jc * NU_;

        // ---- swapped QK^T, both bands share kf ----
#pragma unroll
        for (int nt = 0; nt < 4; ++nt) {
            const short* kr = kbase + (size_t)(nt * 16 + lr) * NU_;
            s8v kf0 = *reinterpret_cast<const s8v*>(kr);
            s8v kf1 = *reinterpret_cast<const s8v*>(kr + 32);
            f4 aA = MFMA16(kf0, qA0, zf);
            f4 sA = MFMA16(kf1, qA1, aA);
            f4 aB = MFMA16(kf0, qB0, zf);
            f4 sB = MFMA16(kf1, qB1, aB);

            const int jl = nt * 16 + lg * 4;   // lane's j base this nt
            float eA[4], eB[4];
#pragma unroll
            for (int r = 0; r < 4; ++r) {
                float vA = __expf(sA[r] * SCALE);
                float vB = __expf(sB[r] * SCALE);
                if (diag && (jl + r > rlocA))      vA = 0.f;
                if (diag && (jl + r > rlocA + 16)) vB = 0.f;
                eA[r] = vA; eB[r] = vB;
            }
            rsumA += (eA[0] + eA[1]) + (eA[2] + eA[3]);
            rsumB += (eB[0] + eB[1]) + (eB[2] + eB[3]);
            const int colp = jl ^ sw;
            s4v pA = { f2bf(eA[0]), f2bf(eA[1]), f2bf(eA[2]), f2bf(eA[3]) };
            s4v pB = { f2bf(eB[0]), f2bf(eB[1]), f2bf(eB[2]), f2bf(eB[3]) };
            *reinterpret_cast<s4v*>(PlA + colp) = pA;
            *reinterpret_cast<s4v*>(PlB + colp) = pB;
        }

        // ---- PV: both bands share vf ----
        s8v pfA0 = *reinterpret_cast<const s8v*>(PlA + ((lg * 8) ^ sw));
        s8v pfA1 = *reinterpret_cast<const s8v*>(PlA + ((32 + lg * 8) ^ sw));
        s8v pfB0 = *reinterpret_cast<const s8v*>(PlB + ((lg * 8) ^ sw));
        s8v pfB1 = *reinterpret_cast<const s8v*>(PlB + ((32 + lg * 8) ^ sw));
#pragma unroll
        for (int nt = 0; nt < 4; ++nt) {
            const short* vr = vt + (size_t)(bh * 64 + nt * 16 + lr) * T_ + jc + lg * 8;
            s8v vf0 = *reinterpret_cast<const s8v*>(vr);
            s8v vf1 = *reinterpret_cast<const s8v*>(vr + 32);
            accA[nt] = MFMA16(pfA0, vf0, accA[nt]);
            accA[nt] = MFMA16(pfA1, vf1, accA[nt]);
            accB[nt] = MFMA16(pfB0, vf0, accB[nt]);
            accB[nt] = MFMA16(pfB1, vf1, accB[nt]);
        }
    }

    // in-wave rowsum combine (lanes lr,lr+16,... hold disjoint j sets)
    rsumA += __shfl_xor(rsumA, 16); rsumA += __shfl_xor(rsumA, 32);
    rsumB += __shfl_xor(rsumB, 16); rsumB += __shfl_xor(rsumB, 32);

    __syncthreads();                            // all Pl reads done (OA alias)
    if (lg == 0) {
        rsbuf[w * 16 + lr]      = rsumA;
        rsbuf[64 + w * 16 + lr] = rsumB;
    }

    // ---- band A reduce + store ----
#pragma unroll
    for (int nt = 0; nt < 4; ++nt)
        st4(&OA[(size_t)(w * 64 + l) * 16 + nt * 4], *(const float4*)&accA[nt]);
    __syncthreads();
    {
        float osum[4] = {0.f, 0.f, 0.f, 0.f};
#pragma unroll
        for (int wv = 0; wv < 4; ++wv) {
            float4 p = *(const float4*)&OA[(size_t)(wv * 64 + l) * 16 + w * 4];
#pragma unroll
            for (int r = 0; r < 4; ++r) osum[r] += (&p.x)[r];
        }
#pragma unroll
        for (int r = 0; r < 4; ++r) {
            const int ro = lg * 4 + r;
            const float rt = rsbuf[ro] + rsbuf[16 + ro] + rsbuf[32 + ro] + rsbuf[48 + ro];
            out[(size_t)(b * T_ + r0 + ro) * NU_ + h * DH_ + w * 16 + lr] = osum[r] / rt;
        }
        if (w == 0 && t < 16) {
            rsws[(size_t)bh * T_ + r0 + t] =
                rsbuf[t] + rsbuf[16 + t] + rsbuf[32 + t] + rsbuf[48 + t];
            rsws[(size_t)bh * T_ + r0 + 16 + t] =
                rsbuf[64 + t] + rsbuf[80 + t] + rsbuf[96 + t] + rsbuf[112 + t];
        }
    }
    __syncthreads();                            // band-A OA reads done

    // ---- band B reduce + store (reuse OA) ----
#pragma unroll
    for (int nt = 0; nt < 4; ++nt)
        st4(&OA[(size_t)(w * 64 + l) * 16 + nt * 4], *(const float4*)&accB[nt]);
    __syncthreads();
    {
        float osum[4] = {0.f, 0.f, 0.f, 0.f};
#pragma unroll
        for (int wv = 0; wv < 4; ++wv) {
            float4 p = *(const float4*)&OA[(size_t)(wv * 64 + l) * 16 + w * 4];
#pragma unroll
            for (int r = 0; r < 4; ++r) osum[r] += (&p.x)[r];
        }
#pragma unroll
        for (int r = 0; r < 4; ++r) {
            const int ro = lg * 4 + r;
            const float rt = rsbuf[64 + ro] + rsbuf[80 + ro] + rsbuf[96 + ro] + rsbuf[112 + ro];
            out[(size_t)(b * T_ + r0 + 16 + ro) * NU_ + h * DH_ + w * 16 + lr] = osum[r] / rt;
        }
    }
}

// ---------------------------------------------------------------------------
// Attention pass B (weights), 2-band: block = 128 q-rows x 256 j-cols.
// Each wave handles two 16-row bands 64 rows apart sharing every K fragment
// (R10's pv mechanism): K-load issue per output halves, 2 independent QK
// chains per nt. Explicit global j<=i masks (both bands' diagonals).
// Cached st4 stores. grid 4096, 256 threads. XCD-chunked; heavy tiles first.
// ---------------------------------------------------------------------------
__global__ __launch_bounds__(256) void attn_wts_mfma(
    const short* __restrict__ qb, const short* __restrict__ kb,
    const float* __restrict__ rsws, float* __restrict__ wts)
{
    const int lin = blockIdx.x;
    const int xcd = lin & 7, v = lin >> 3;     // 0..511
    const int bh  = xcd * 4 + (v >> 7);
    const int rem = v & 127;
    const int qt2 = 15 - (rem >> 3);           // heavy 128-row tiles first
    const int jb  = rem & 7;
    const int b = bh >> 4, h = bh & 15;
    const int r0 = qt2 * 128;
    const int chmax = 2 * qt2 + 1;             // last chunk with any score work
    const int t = threadIdx.x, w = t >> 6, l = t & 63;
    const int lr = l & 15, lg = l >> 4;

    const int iA = r0 + w * 16 + lr;            // band-A q-row
    const int iB = iA + 64;                     // band-B q-row

    const short* qrowA = qb + (size_t)(b * T_ + iA) * NU_ + h * DH_ + lg * 8;
    const s8v qA0 = *reinterpret_cast<const s8v*>(qrowA);
    const s8v qA1 = *reinterpret_cast<const s8v*>(qrowA + 32);
    const s8v qB0 = *reinterpret_cast<const s8v*>(qrowA + 64 * NU_);
    const s8v qB1 = *reinterpret_cast<const s8v*>(qrowA + 64 * NU_ + 32);
    const f4 zf = (f4){0.f, 0.f, 0.f, 0.f};

    const float invA = 1.f / rsws[(size_t)bh * T_ + iA];
    const float invB = 1.f / rsws[(size_t)bh * T_ + iB];
    float* const wrowA = &wts[((size_t)bh * T_ + iA) * T_];
    float* const wrowB = &wts[((size_t)bh * T_ + iB) * T_];
    const short* kbase0 = kb + (size_t)(b * T_) * NU_ + h * DH_ + lg * 8;

#pragma unroll
    for (int cx = 0; cx < 4; ++cx) {
        const int ch = jb * 4 + cx;
        const int jc = ch * 64;
        if (ch <= chmax) {
            const short* kbase = kbase0 + (size_t)jc * NU_;
            f4 sA[4], sB[4];
#pragma unroll
            for (int nt = 0; nt < 4; ++nt) {
                const short* kr = kbase + (size_t)(nt * 16 + lr) * NU_;
                s8v kf0 = *reinterpret_cast<const s8v*>(kr);
                s8v kf1 = *reinterpret_cast<const s8v*>(kr + 32);
                f4 aA = MFMA16(kf0, qA0, zf);
                sA[nt] = MFMA16(kf1, qA1, aA);
                f4 aB = MFMA16(kf0, qB0, zf);
                sB[nt] = MFMA16(kf1, qB1, aB);
            }
#pragma unroll
            for (int nt = 0; nt < 4; ++nt) {
                float4 oA, oB;
                float* eA = &oA.x;
                float* eB = &oB.x;
#pragma unroll
                for (int r = 0; r < 4; ++r) {
                    const int j = jc + nt * 16 + lg * 4 + r;
                    eA[r] = (j <= iA) ? __expf(sA[nt][r] * SCALE) * invA : 0.f;
                    eB[r] = (j <= iB) ? __expf(sB[nt][r] * SCALE) * invB : 0.f;
                }
                st4(wrowA + jc + nt * 16 + lg * 4, oA);
                st4(wrowB + jc + nt * 16 + lg * 4, oB);
            }
        } else {
            // chunk fully above both bands' diagonals: zero-fill 128 rows
            const float4 z4 = make_float4(0.f, 0.f, 0.f, 0.f);
#pragma unroll
            for (int half = 0; half < 2; ++half) {
                float* dst = &wts[((size_t)bh * T_ + r0 + half * 64 + (t >> 2)) * T_
                                  + jc + (t & 3) * 16];
                st4(dst + 0, z4); st4(dst + 4, z4);
                st4(dst + 8, z4); st4(dst + 12, z4);
            }
        }
    }
}

// ---------------------------------------------------------------------------
extern "C" void kernel_launch(void* const* d_in, const int* in_sizes, int n_in,
                              void* d_out, int out_size, void* d_ws, size_t ws_size,
                              hipStream_t stream)
{
    const float* queries = (const float*)d_in[0];
    const float* keys    = (const float*)d_in[1];
    const float* Wq = (const float*)d_in[2];
    const float* bq = (const float*)d_in[3];
    const float* Wk = (const float*)d_in[4];
    const float* bk = (const float*)d_in[5];
    const float* Wv = (const float*)d_in[6];
    const float* bv = (const float*)d_in[7];

    float* out = (float*)d_out;                 // [B,T,NU]
    float* wts = out + OUT_ELEMS;               // [B,H,T,T]

    // workspace (bf16 shorts unless noted), total ~44.3 MB:
    short* qx = (short*)d_ws;                               // queries bf16 [4096][1024]
    short* kx = qx + (size_t)B_ * T_ * D_;                  // keys bf16
    short* wt = kx + (size_t)B_ * T_ * D_;                  // Wt bf16 [3][N][K]
    short* qb = wt + (size_t)3 * D_ * NU_;                  // q proj bf16 [4096][1024]
    short* kb = qb + (size_t)B_ * T_ * NU_;                 // k proj bf16
    short* vt = kb + (size_t)B_ * T_ * NU_;                 // v proj bf16, [bh][d][t]
    float* rsws = (float*)(vt + (size_t)B_ * T_ * NU_);     // rowsums [bh][t]

    cvt_x_kernel<<<dim3((B_ * T_ * D_) / 2048, 2), 256, 0, stream>>>(queries, keys, qx, kx);
    cvt_w_kernel<<<dim3(16, 16, 3), 256, 0, stream>>>(Wq, Wk, Wv, wt);
    proj_mfma<<<dim3(8, 32, 3), 256, 0, stream>>>(
        qx, kx, wt, bq, bk, bv, qb, kb, vt);
    attn_pv_mfma<<<dim3(2048), 256, 0, stream>>>(qb, kb, vt, rsws, out);
    attn_wts_mfma<<<dim3(4096), 256, 0, stream>>>(qb, kb, rsws, wts);
}

// Round 12
// 283.831 us; speedup vs baseline: 1.5082x; 1.0415x over previous
//
#include <hip/hip_runtime.h>
#include <cstddef>
#include <cstdint>

// Problem constants (reference: B=2, T=2048, D=1024, H=16, DH=64, NU=1024)
namespace {
constexpr int B_ = 2, T_ = 2048, D_ = 1024, H_ = 16, DH_ = 64, NU_ = 1024;
constexpr float SCALE = 0.03125f;           // NU^-0.5 = 1/32
constexpr size_t OUT_ELEMS = (size_t)B_ * T_ * NU_;   // 4,194,304
}

using f4  = __attribute__((ext_vector_type(4))) float;
using s8v = __attribute__((ext_vector_type(8))) short;   // 8 bf16 (4 VGPRs)
using s4v = __attribute__((ext_vector_type(4))) short;

#define MFMA16(a, b, c) __builtin_amdgcn_mfma_f32_16x16x32_bf16((a), (b), (c), 0, 0, 0)

__device__ __forceinline__ float4 ld4(const float* p) { return *reinterpret_cast<const float4*>(p); }
__device__ __forceinline__ void st4(float* p, const float4 v) { *reinterpret_cast<float4*>(p) = v; }
__device__ __forceinline__ short f2bf(float f) {      // fp32 -> bf16 RNE
    union { float f; uint32_t u; } v{f};
    uint32_t r = (v.u + 0x7fffu + ((v.u >> 16) & 1u)) >> 16;
    return (short)r;
}

#if __has_builtin(__builtin_amdgcn_global_load_lds)
#define HAVE_GLOAD_LDS 1
__device__ __forceinline__ void load_lds16(const void* g, void* l) {
    __builtin_amdgcn_global_load_lds(
        (const __attribute__((address_space(1))) void*)g,
        (__attribute__((address_space(3))) void*)l, 16, 0, 0);
}
#else
#define HAVE_GLOAD_LDS 0
#endif

// ---------------------------------------------------------------------------
// Convert queries/keys fp32 -> bf16 row-major. grid (N/2048, 2).
// ---------------------------------------------------------------------------
__global__ __launch_bounds__(256) void cvt_x_kernel(
    const float* __restrict__ q, const float* __restrict__ k,
    short* __restrict__ qx, short* __restrict__ kx)
{
    const float* src = blockIdx.y ? k : q;
    short* dst       = blockIdx.y ? kx : qx;
    size_t i = ((size_t)blockIdx.x * 256 + threadIdx.x) * 8;
    float4 a = ld4(src + i), b = ld4(src + i + 4);
    s8v o = { f2bf(a.x), f2bf(a.y), f2bf(a.z), f2bf(a.w),
              f2bf(b.x), f2bf(b.y), f2bf(b.z), f2bf(b.w) };
    *reinterpret_cast<s8v*>(dst + i) = o;
}

// ---------------------------------------------------------------------------
// Convert + transpose W fp32 [K][N] -> bf16 Wt [N][K]. grid (16,16,3).
// ---------------------------------------------------------------------------
__global__ __launch_bounds__(256) void cvt_w_kernel(
    const float* __restrict__ Wq, const float* __restrict__ Wk,
    const float* __restrict__ Wv, short* __restrict__ wt3)
{
    const int z = blockIdx.z;
    const float* W = (z == 0) ? Wq : (z == 1) ? Wk : Wv;
    short* dst = wt3 + (size_t)z * D_ * NU_;
    const int n0 = blockIdx.x * 64, k0 = blockIdx.y * 64;
    __shared__ float tl[64][68];
    const int rr = threadIdx.x >> 2, cc = (threadIdx.x & 3) * 16;
    const float* s = W + (size_t)(k0 + rr) * NU_ + n0 + cc;
    st4(&tl[rr][cc + 0],  ld4(s + 0));
    st4(&tl[rr][cc + 4],  ld4(s + 4));
    st4(&tl[rr][cc + 8],  ld4(s + 8));
    st4(&tl[rr][cc + 12], ld4(s + 12));
    __syncthreads();
    short* d = dst + (size_t)(n0 + rr) * D_ + k0 + cc;
#pragma unroll
    for (int c = 0; c < 4; ++c) {
        s4v o = { f2bf(tl[cc + c * 4 + 0][rr]), f2bf(tl[cc + c * 4 + 1][rr]),
                  f2bf(tl[cc + c * 4 + 2][rr]), f2bf(tl[cc + c * 4 + 3][rr]) };
        *reinterpret_cast<s4v*>(d + c * 4) = o;
    }
}

// ---------------------------------------------------------------------------
// QKV projection, bf16 MFMA: 128x128 tile, BK=64, 4 waves, global_load_lds
// width-16 into linear [128][64] LDS. XCD-chunked remap (768 = 8 x 96).
// z=0->qb, z=1->kb, z=2->vt ([bh][d][t] transposed). grid(8,32,3), 256 thr.
// ---------------------------------------------------------------------------
__global__ __launch_bounds__(256) void proj_mfma(
    const short* __restrict__ qx, const short* __restrict__ kx,
    const short* __restrict__ wt3,
    const float* __restrict__ bq, const float* __restrict__ bk,
    const float* __restrict__ bv,
    short* __restrict__ qb, short* __restrict__ kb, short* __restrict__ vt)
{
    const int lin = blockIdx.z * 256 + blockIdx.y * 8 + blockIdx.x;
    const int virt = (lin & 7) * 96 + (lin >> 3);
    const int z = virt >> 8, rem = virt & 255;
    const int m0 = (rem >> 3) * 128, n0 = (rem & 7) * 128;

    const short* __restrict__ X  = (z == 0) ? qx : kx;
    const short* __restrict__ Wt = wt3 + (size_t)z * D_ * NU_;
    const float* __restrict__ bias = (z == 0) ? bq : (z == 1) ? bk : bv;

    const int t = threadIdx.x, w = t >> 6, l = t & 63;
    const int lr = l & 15, lg = l >> 4;
    const int wr = w >> 1, wc = w & 1;

    __shared__ short Asl[128 * 64];   // [row][k] linear, 16KB
    __shared__ short Bsl[128 * 64];   // [n][k] linear, 16KB

    f4 acc[4][4];
#pragma unroll
    for (int m = 0; m < 4; ++m)
#pragma unroll
        for (int n = 0; n < 4; ++n) acc[m][n] = (f4){0.f, 0.f, 0.f, 0.f};

    for (int k0 = 0; k0 < D_; k0 += 64) {
#if HAVE_GLOAD_LDS
#pragma unroll
        for (int j = 0; j < 4; ++j) {
            const int c0 = (w * 4 + j) * 64;
            const int c  = c0 + l;
            const int row = c >> 3, qo = (c & 7) * 8;
            load_lds16(X  + (size_t)(m0 + row) * D_ + k0 + qo, (char*)Asl + (size_t)c0 * 16);
            load_lds16(Wt + (size_t)(n0 + row) * D_ + k0 + qo, (char*)Bsl + (size_t)c0 * 16);
        }
        __syncthreads();
#else
        {
            const int sr = t >> 1, sc = (t & 1) * 32;
            s8v a0 = *reinterpret_cast<const s8v*>(X  + (size_t)(m0 + sr) * D_ + k0 + sc);
            s8v a1 = *reinterpret_cast<const s8v*>(X  + (size_t)(m0 + sr) * D_ + k0 + sc + 8);
            s8v a2 = *reinterpret_cast<const s8v*>(X  + (size_t)(m0 + sr) * D_ + k0 + sc + 16);
            s8v a3 = *reinterpret_cast<const s8v*>(X  + (size_t)(m0 + sr) * D_ + k0 + sc + 24);
            s8v b0 = *reinterpret_cast<const s8v*>(Wt + (size_t)(n0 + sr) * D_ + k0 + sc);
            s8v b1 = *reinterpret_cast<const s8v*>(Wt + (size_t)(n0 + sr) * D_ + k0 + sc + 8);
            s8v b2 = *reinterpret_cast<const s8v*>(Wt + (size_t)(n0 + sr) * D_ + k0 + sc + 16);
            s8v b3 = *reinterpret_cast<const s8v*>(Wt + (size_t)(n0 + sr) * D_ + k0 + sc + 24);
            __syncthreads();
            *reinterpret_cast<s8v*>(&Asl[sr * 64 + sc])      = a0;
            *reinterpret_cast<s8v*>(&Asl[sr * 64 + sc + 8])  = a1;
            *reinterpret_cast<s8v*>(&Asl[sr * 64 + sc + 16]) = a2;
            *reinterpret_cast<s8v*>(&Asl[sr * 64 + sc + 24]) = a3;
            *reinterpret_cast<s8v*>(&Bsl[sr * 64 + sc])      = b0;
            *reinterpret_cast<s8v*>(&Bsl[sr * 64 + sc + 8])  = b1;
            *reinterpret_cast<s8v*>(&Bsl[sr * 64 + sc + 16]) = b2;
            *reinterpret_cast<s8v*>(&Bsl[sr * 64 + sc + 24]) = b3;
            __syncthreads();
        }
#endif

#pragma unroll
        for (int kk = 0; kk < 2; ++kk) {
            s8v af[4], bf[4];
#pragma unroll
            for (int m = 0; m < 4; ++m)
                af[m] = *reinterpret_cast<const s8v*>(
                    &Asl[(wr * 64 + m * 16 + lr) * 64 + kk * 32 + lg * 8]);
#pragma unroll
            for (int n = 0; n < 4; ++n)
                bf[n] = *reinterpret_cast<const s8v*>(
                    &Bsl[(wc * 64 + n * 16 + lr) * 64 + kk * 32 + lg * 8]);
#pragma unroll
            for (int m = 0; m < 4; ++m)
#pragma unroll
                for (int n = 0; n < 4; ++n)
                    acc[m][n] = MFMA16(af[m], bf[n], acc[m][n]);
        }
        __syncthreads();
    }

    if (z < 2) {
        short* __restrict__ Y = (z == 0) ? qb : kb;
#pragma unroll
        for (int n = 0; n < 4; ++n) {
            const int col = n0 + wc * 64 + n * 16 + lr;
            const float bval = bias[col];
#pragma unroll
            for (int m = 0; m < 4; ++m) {
                const int row0 = m0 + wr * 64 + m * 16 + lg * 4;
#pragma unroll
                for (int r = 0; r < 4; ++r)
                    Y[(size_t)(row0 + r) * NU_ + col] = f2bf(acc[m][n][r] + bval);
            }
        }
    } else {
#pragma unroll
        for (int n = 0; n < 4; ++n) {
            const int col = n0 + wc * 64 + n * 16 + lr;   // 0..1023
            const float bval = bias[col];
            const int hh = col >> 6, dd = col & 63;
#pragma unroll
            for (int m = 0; m < 4; ++m) {
                const int Mi = m0 + wr * 64 + m * 16 + lg * 4;
                const int bb = Mi >> 11, t0 = Mi & 2047;
                s4v o = { f2bf(acc[m][n][0] + bval), f2bf(acc[m][n][1] + bval),
                          f2bf(acc[m][n][2] + bval), f2bf(acc[m][n][3] + bval) };
                *reinterpret_cast<s4v*>(vt + ((size_t)(bb * 16 + hh) * 64 + dd) * T_ + t0) = o;
            }
        }
    }
}

// ---------------------------------------------------------------------------
// Attention pass A (PV + rowsums + out), 4-band 64-row blocks: four 16-row
// bands share every K/V fragment (R10's mechanism deepened: K/V-load issue
// per output row is 1/4 of the 16-row form; 4 independent MFMA chains per
// fragment). Waves split the chunk range (w, w+4, ...). P buffers: per-band
// per-wave LDS (32KB), barrier-free loop. Epilogue: 4-pass band loop over
// the aliased 16KB OA buffer. grid 1024, 256 threads. XCD-chunked.
// ---------------------------------------------------------------------------
__global__ __launch_bounds__(256) void attn_pv_mfma(
    const short* __restrict__ qb, const short* __restrict__ kb,
    const short* __restrict__ vt, float* __restrict__ rsws,
    float* __restrict__ out)
{
    const int lin = blockIdx.x;
    const int xcd = lin & 7, v = lin >> 3;     // v: 0..127
    const int bh  = xcd * 4 + (v >> 5);
    const int g64 = 31 - (v & 31);             // heavy 64-row tiles first
    const int b = bh >> 4, h = bh & 15;
    const int r0 = g64 * 64;
    const int t = threadIdx.x, w = t >> 6, l = t & 63;
    const int lr = l & 15, lg = l >> 4;
    const int tile16 = g64;                    // diagonal chunk (r0/64)
    // band d's row pos within diag chunk = d*16 + lr

    __shared__ __align__(16) char smem[32 * 1024 + 1024];
    short* Pl    = (short*)smem;               // [band][wave][16][64] bf16, 32KB
    float* OA    = (float*)smem;               // 16KB alias (post-barrier)
    float* rsbuf = (float*)(smem + 32 * 1024); // [band][64]

    // Q fragments, 4 bands (B-operand: col=lane&15=q-row)
    const short* qrow0 = qb + (size_t)(b * T_ + r0 + lr) * NU_ + h * DH_ + lg * 8;
    s8v qf[4][2];
#pragma unroll
    for (int d = 0; d < 4; ++d) {
        qf[d][0] = *reinterpret_cast<const s8v*>(qrow0 + (size_t)d * 16 * NU_);
        qf[d][1] = *reinterpret_cast<const s8v*>(qrow0 + (size_t)d * 16 * NU_ + 32);
    }

    f4 acc[4][4];                              // [band][nt]
#pragma unroll
    for (int d = 0; d < 4; ++d)
#pragma unroll
        for (int nt = 0; nt < 4; ++nt) acc[d][nt] = (f4){0.f, 0.f, 0.f, 0.f};
    float rsum[4] = {0.f, 0.f, 0.f, 0.f};
    const f4 zf = (f4){0.f, 0.f, 0.f, 0.f};
    const int sw = (lr & 7) << 3;              // P swizzle keyed on q-row
    const short* kbase0 = kb + (size_t)(b * T_) * NU_ + h * DH_ + lg * 8;
    short* PlW[4];
#pragma unroll
    for (int d = 0; d < 4; ++d) PlW[d] = &Pl[d * 4096 + w * 1024 + lr * 64];

    for (int ch = w; ch <= tile16; ch += 4) {
        const int jc = ch * 64;
        const bool diag = (ch == tile16);
        const short* kbase = kbase0 + (size_t)jc * NU_;

        // ---- swapped QK^T + exp + P-write; all 4 bands share kf ----
#pragma unroll
        for (int nt = 0; nt < 4; ++nt) {
            const short* kr = kbase + (size_t)(nt * 16 + lr) * NU_;
            s8v kf0 = *reinterpret_cast<const s8v*>(kr);
            s8v kf1 = *reinterpret_cast<const s8v*>(kr + 32);
            const int jl = nt * 16 + lg * 4;   // lane's j base this nt
#pragma unroll
            for (int d = 0; d < 4; ++d) {
                f4 a = MFMA16(kf0, qf[d][0], zf);
                f4 s = MFMA16(kf1, qf[d][1], a);
                float e[4];
#pragma unroll
                for (int r = 0; r < 4; ++r) {
                    float vv = __expf(s[r] * SCALE);
                    if (diag && (jl + r > d * 16 + lr)) vv = 0.f;
                    e[r] = vv;
                }
                rsum[d] += (e[0] + e[1]) + (e[2] + e[3]);
                s4v pv = { f2bf(e[0]), f2bf(e[1]), f2bf(e[2]), f2bf(e[3]) };
                *reinterpret_cast<s4v*>(PlW[d] + (jl ^ sw)) = pv;
            }
        }

        // ---- PV: all 4 bands share vf ----
        s8v pf[4][2];
#pragma unroll
        for (int d = 0; d < 4; ++d) {
            pf[d][0] = *reinterpret_cast<const s8v*>(PlW[d] + ((lg * 8) ^ sw));
            pf[d][1] = *reinterpret_cast<const s8v*>(PlW[d] + ((32 + lg * 8) ^ sw));
        }
#pragma unroll
        for (int nt = 0; nt < 4; ++nt) {
            const short* vr = vt + (size_t)(bh * 64 + nt * 16 + lr) * T_ + jc + lg * 8;
            s8v vf0 = *reinterpret_cast<const s8v*>(vr);
            s8v vf1 = *reinterpret_cast<const s8v*>(vr + 32);
#pragma unroll
            for (int d = 0; d < 4; ++d) {
                acc[d][nt] = MFMA16(pf[d][0], vf0, acc[d][nt]);
                acc[d][nt] = MFMA16(pf[d][1], vf1, acc[d][nt]);
            }
        }
    }

    // in-wave rowsum combine (lanes lr,lr+16,... hold disjoint j sets)
#pragma unroll
    for (int d = 0; d < 4; ++d) {
        rsum[d] += __shfl_xor(rsum[d], 16);
        rsum[d] += __shfl_xor(rsum[d], 32);
    }

    __syncthreads();                            // all Pl reads done (OA alias)
    if (lg == 0) {
#pragma unroll
        for (int d = 0; d < 4; ++d) rsbuf[d * 64 + w * 16 + lr] = rsum[d];
    }

    // ---- 4-pass band reduce + store over aliased OA ----
#pragma unroll
    for (int d = 0; d < 4; ++d) {
#pragma unroll
        for (int nt = 0; nt < 4; ++nt)
            st4(&OA[(size_t)(w * 64 + l) * 16 + nt * 4], *(const float4*)&acc[d][nt]);
        __syncthreads();                        // OA ready (rsbuf also visible)
        float osum[4] = {0.f, 0.f, 0.f, 0.f};
#pragma unroll
        for (int wv = 0; wv < 4; ++wv) {
            float4 p = *(const float4*)&OA[(size_t)(wv * 64 + l) * 16 + w * 4];
#pragma unroll
            for (int r = 0; r < 4; ++r) osum[r] += (&p.x)[r];
        }
#pragma unroll
        for (int r = 0; r < 4; ++r) {
            const int ro = lg * 4 + r;         // local row in band 0..15
            const float rt = rsbuf[d * 64 + ro] + rsbuf[d * 64 + 16 + ro]
                           + rsbuf[d * 64 + 32 + ro] + rsbuf[d * 64 + 48 + ro];
            out[(size_t)(b * T_ + r0 + d * 16 + ro) * NU_ + h * DH_ + w * 16 + lr] =
                osum[r] / rt;
        }
        if (w == 0 && t < 16)
            rsws[(size_t)bh * T_ + r0 + d * 16 + t] =
                rsbuf[d * 64 + t] + rsbuf[d * 64 + 16 + t]
                + rsbuf[d * 64 + 32 + t] + rsbuf[d * 64 + 48 + t];
        __syncthreads();                        // OA reads done before next band
    }
}

// ---------------------------------------------------------------------------
// Attention pass B (weights), 2-band: block = 128 q-rows x 256 j-cols.
// Each wave handles two 16-row bands 64 rows apart sharing every K fragment
// (R11 structure, -11us). Cached st4 stores. grid 4096, 256 threads.
// ---------------------------------------------------------------------------
__global__ __launch_bounds__(256) void attn_wts_mfma(
    const short* __restrict__ qb, const short* __restrict__ kb,
    const float* __restrict__ rsws, float* __restrict__ wts)
{
    const int lin = blockIdx.x;
    const int xcd = lin & 7, v = lin >> 3;     // 0..511
    const int bh  = xcd * 4 + (v >> 7);
    const int rem = v & 127;
    const int qt2 = 15 - (rem >> 3);           // heavy 128-row tiles first
    const int jb  = rem & 7;
    const int b = bh >> 4, h = bh & 15;
    const int r0 = qt2 * 128;
    const int chmax = 2 * qt2 + 1;             // last chunk with any score work
    const int t = threadIdx.x, w = t >> 6, l = t & 63;
    const int lr = l & 15, lg = l >> 4;

    const int iA = r0 + w * 16 + lr;            // band-A q-row
    const int iB = iA + 64;                     // band-B q-row

    const short* qrowA = qb + (size_t)(b * T_ + iA) * NU_ + h * DH_ + lg * 8;
    const s8v qA0 = *reinterpret_cast<const s8v*>(qrowA);
    const s8v qA1 = *reinterpret_cast<const s8v*>(qrowA + 32);
    const s8v qB0 = *reinterpret_cast<const s8v*>(qrowA + 64 * NU_);
    const s8v qB1 = *reinterpret_cast<const s8v*>(qrowA + 64 * NU_ + 32);
    const f4 zf = (f4){0.f, 0.f, 0.f, 0.f};

    const float invA = 1.f / rsws[(size_t)bh * T_ + iA];
    const float invB = 1.f / rsws[(size_t)bh * T_ + iB];
    float* const wrowA = &wts[((size_t)bh * T_ + iA) * T_];
    float* const wrowB = &wts[((size_t)bh * T_ + iB) * T_];
    const short* kbase0 = kb + (size_t)(b * T_) * NU_ + h * DH_ + lg * 8;

#pragma unroll
    for (int cx = 0; cx < 4; ++cx) {
        const int ch = jb * 4 + cx;
        const int jc = ch * 64;
        if (ch <= chmax) {
            const short* kbase = kbase0 + (size_t)jc * NU_;
            f4 sA[4], sB[4];
#pragma unroll
            for (int nt = 0; nt < 4; ++nt) {
                const short* kr = kbase + (size_t)(nt * 16 + lr) * NU_;
                s8v kf0 = *reinterpret_cast<const s8v*>(kr);
                s8v kf1 = *reinterpret_cast<const s8v*>(kr + 32);
                f4 aA = MFMA16(kf0, qA0, zf);
                sA[nt] = MFMA16(kf1, qA1, aA);
                f4 aB = MFMA16(kf0, qB0, zf);
                sB[nt] = MFMA16(kf1, qB1, aB);
            }
#pragma unroll
            for (int nt = 0; nt < 4; ++nt) {
                float4 oA, oB;
                float* eA = &oA.x;
                float* eB = &oB.x;
#pragma unroll
                for (int r = 0; r < 4; ++r) {
                    const int j = jc + nt * 16 + lg * 4 + r;
                    eA[r] = (j <= iA) ? __expf(sA[nt][r] * SCALE) * invA : 0.f;
                    eB[r] = (j <= iB) ? __expf(sB[nt][r] * SCALE) * invB : 0.f;
                }
                st4(wrowA + jc + nt * 16 + lg * 4, oA);
                st4(wrowB + jc + nt * 16 + lg * 4, oB);
            }
        } else {
            // chunk fully above both bands' diagonals: zero-fill 128 rows
            const float4 z4 = make_float4(0.f, 0.f, 0.f, 0.f);
#pragma unroll
            for (int half = 0; half < 2; ++half) {
                float* dst = &wts[((size_t)bh * T_ + r0 + half * 64 + (t >> 2)) * T_
                                  + jc + (t & 3) * 16];
                st4(dst + 0, z4); st4(dst + 4, z4);
                st4(dst + 8, z4); st4(dst + 12, z4);
            }
        }
    }
}

// ---------------------------------------------------------------------------
extern "C" void kernel_launch(void* const* d_in, const int* in_sizes, int n_in,
                              void* d_out, int out_size, void* d_ws, size_t ws_size,
                              hipStream_t stream)
{
    const float* queries = (const float*)d_in[0];
    const float* keys    = (const float*)d_in[1];
    const float* Wq = (const float*)d_in[2];
    const float* bq = (const float*)d_in[3];
    const float* Wk = (const float*)d_in[4];
    const float* bk = (const float*)d_in[5];
    const float* Wv = (const float*)d_in[6];
    const float* bv = (const float*)d_in[7];

    float* out = (float*)d_out;                 // [B,T,NU]
    float* wts = out + OUT_ELEMS;               // [B,H,T,T]

    // workspace (bf16 shorts unless noted), total ~44.3 MB:
    short* qx = (short*)d_ws;                               // queries bf16 [4096][1024]
    short* kx = qx + (size_t)B_ * T_ * D_;                  // keys bf16
    short* wt = kx + (size_t)B_ * T_ * D_;                  // Wt bf16 [3][N][K]
    short* qb = wt + (size_t)3 * D_ * NU_;                  // q proj bf16 [4096][1024]
    short* kb = qb + (size_t)B_ * T_ * NU_;                 // k proj bf16
    short* vt = kb + (size_t)B_ * T_ * NU_;                 // v proj bf16, [bh][d][t]
    float* rsws = (float*)(vt + (size_t)B_ * T_ * NU_);     // rowsums [bh][t]

    cvt_x_kernel<<<dim3((B_ * T_ * D_) / 2048, 2), 256, 0, stream>>>(queries, keys, qx, kx);
    cvt_w_kernel<<<dim3(16, 16, 3), 256, 0, stream>>>(Wq, Wk, Wv, wt);
    proj_mfma<<<dim3(8, 32, 3), 256, 0, stream>>>(
        qx, kx, wt, bq, bk, bv, qb, kb, vt);
    attn_pv_mfma<<<dim3(1024), 256, 0, stream>>>(qb, kb, vt, rsws, out);
    attn_wts_mfma<<<dim3(4096), 256, 0, stream>>>(qb, kb, rsws, wts);
}